// Round 1
// baseline (585.425 us; speedup 1.0000x reference)
//
#include <hip/hip_runtime.h>
#include <hip/hip_bf16.h>

// Problem constants (B=1)
#define T_DIM 4096
#define E_DIM 1024
#define H_DIM 16
#define HD_DIM 64
#define SCALE_F 0.125f   // 8.0 / HD

typedef __bf16 bf16_t;
typedef __bf16 bf16x8 __attribute__((ext_vector_type(8)));
typedef float  f32x4  __attribute__((ext_vector_type(4)));

// ---- staging helpers: load 8 elements, convert to bf16, 16B LDS write ----
__device__ inline void stage8(bf16_t* dst, const float* src) {
  const f32x4* s4 = (const f32x4*)src;
  f32x4 a = s4[0], b = s4[1];
  bf16x8 o;
  o[0] = (bf16_t)a[0]; o[1] = (bf16_t)a[1]; o[2] = (bf16_t)a[2]; o[3] = (bf16_t)a[3];
  o[4] = (bf16_t)b[0]; o[5] = (bf16_t)b[1]; o[6] = (bf16_t)b[2]; o[7] = (bf16_t)b[3];
  *(bf16x8*)dst = o;
}
__device__ inline void stage8(bf16_t* dst, const bf16_t* src) {
  *(bf16x8*)dst = *(const bf16x8*)src;
}

// ---- GEMM: C[M][N] = A[M][K] x B[N][K]^T (both row-major, K contiguous) ----
// 128x128 tile, BK=32, 256 threads (4 waves, 2x2), each wave 64x64 via 4x4
// mfma_f32_16x16x32_bf16 fragments.
template <typename TA, typename TB, typename TC>
__global__ __launch_bounds__(256) void gemm_bt(const TA* __restrict__ A,
                                               const TB* __restrict__ B,
                                               TC* __restrict__ C,
                                               int M, int N, int K) {
  __shared__ alignas(16) bf16_t As[128][40];  // pad 32->40: 2-way bank alias (free)
  __shared__ alignas(16) bf16_t Bs[128][40];
  const int tid  = threadIdx.x;
  const int lane = tid & 63, w = tid >> 6;
  const int g = lane >> 4, l15 = lane & 15;
  const int wr = w >> 1, wc = w & 1;
  const int bm = blockIdx.y * 128, bn = blockIdx.x * 128;

  f32x4 acc[4][4] = {};

  for (int kt = 0; kt < K; kt += 32) {
    __syncthreads();
#pragma unroll
    for (int i = 0; i < 2; ++i) {
      int v   = tid + i * 256;        // 512 vec8 slots = 128 rows x 4 col-groups
      int row = v >> 2, c8 = (v & 3) * 8;
      stage8(&As[row][c8], &A[(size_t)(bm + row) * K + kt + c8]);
      stage8(&Bs[row][c8], &B[(size_t)(bn + row) * K + kt + c8]);
    }
    __syncthreads();

    bf16x8 af[4], bfr[4];
#pragma unroll
    for (int m = 0; m < 4; ++m)
      af[m] = *(const bf16x8*)&As[wr * 64 + m * 16 + l15][g * 8];
#pragma unroll
    for (int n = 0; n < 4; ++n)
      bfr[n] = *(const bf16x8*)&Bs[wc * 64 + n * 16 + l15][g * 8];
#pragma unroll
    for (int m = 0; m < 4; ++m)
#pragma unroll
      for (int n = 0; n < 4; ++n)
        acc[m][n] = __builtin_amdgcn_mfma_f32_16x16x32_bf16(af[m], bfr[n], acc[m][n], 0, 0, 0);
  }

  // epilogue: C/D layout col=lane&15, row=(lane>>4)*4+reg
#pragma unroll
  for (int m = 0; m < 4; ++m)
#pragma unroll
    for (int n = 0; n < 4; ++n)
#pragma unroll
      for (int r = 0; r < 4; ++r) {
        int row = bm + wr * 64 + m * 16 + g * 4 + r;
        int col = bn + wc * 64 + n * 16 + l15;
        C[(size_t)row * N + col] = (TC)acc[m][n][r];
      }
}

// ---- Flash attention, causal, online softmax ----
// grid (T/64, H), 256 threads (4 waves). Wave w owns Q rows qt+w*16 .. +16.
// Qp,Kp: [T][E] bf16 (head h at cols h*64..h*64+63). Vt: [E][T] bf16.
__global__ __launch_bounds__(256) void attn_fwd(const bf16_t* __restrict__ Qp,
                                                const bf16_t* __restrict__ Kp,
                                                const bf16_t* __restrict__ Vt,
                                                bf16_t* __restrict__ Oattn) {
  const int h  = blockIdx.y;
  const int qi = (T_DIM / 64 - 1) - blockIdx.x;  // big blocks first
  const int tid = threadIdx.x, lane = tid & 63, w = tid >> 6;
  const int g = lane >> 4, l15 = lane & 15;
  const int qt = qi * 64;
  const int qrow = qt + w * 16;

  __shared__ alignas(16) bf16_t Plds[4][16][72];  // per-wave P, padded

  bf16x8 qf[2];
  {
    const bf16_t* qp = &Qp[(size_t)(qrow + l15) * E_DIM + h * 64 + g * 8];
    qf[0] = *(const bf16x8*)qp;
    qf[1] = *(const bf16x8*)(qp + 32);
  }

  f32x4 acc[4] = {};
  float m_r[4], l_r[4];
#pragma unroll
  for (int r = 0; r < 4; ++r) { m_r[r] = -1e30f; l_r[r] = 0.f; }

  for (int j = 0; j <= qi; ++j) {
    const int kb = j * 64;
    // S = Q K^T  (wave: 16 rows x 64 cols)
    f32x4 s[4] = {};
#pragma unroll
    for (int j16 = 0; j16 < 4; ++j16) {
      const bf16_t* kp = &Kp[(size_t)(kb + j16 * 16 + l15) * E_DIM + h * 64 + g * 8];
      s[j16] = __builtin_amdgcn_mfma_f32_16x16x32_bf16(qf[0], *(const bf16x8*)kp,        s[j16], 0, 0, 0);
      s[j16] = __builtin_amdgcn_mfma_f32_16x16x32_bf16(qf[1], *(const bf16x8*)(kp + 32), s[j16], 0, 0, 0);
    }
    // scale + causal mask (only diagonal tile needs masking)
    const bool diag = (j == qi);
#pragma unroll
    for (int j16 = 0; j16 < 4; ++j16)
#pragma unroll
      for (int r = 0; r < 4; ++r) {
        float sv = s[j16][r] * SCALE_F;
        if (diag && (kb + j16 * 16 + l15 > qrow + g * 4 + r)) sv = -1e30f;
        s[j16][r] = sv;
      }
    // row max (16 lanes of group g hold 16 cols of row g*4+r per fragment)
    float rmax[4], mnew[4], sc[4], rsum[4];
#pragma unroll
    for (int r = 0; r < 4; ++r)
      rmax[r] = fmaxf(fmaxf(s[0][r], s[1][r]), fmaxf(s[2][r], s[3][r]));
#pragma unroll
    for (int off = 1; off < 16; off <<= 1)
#pragma unroll
      for (int r = 0; r < 4; ++r)
        rmax[r] = fmaxf(rmax[r], __shfl_xor(rmax[r], off));
#pragma unroll
    for (int r = 0; r < 4; ++r) {
      mnew[r] = fmaxf(m_r[r], rmax[r]);
      sc[r]   = __expf(m_r[r] - mnew[r]);
    }
#pragma unroll
    for (int j16 = 0; j16 < 4; ++j16)
#pragma unroll
      for (int r = 0; r < 4; ++r)
        s[j16][r] = __expf(s[j16][r] - mnew[r]);
#pragma unroll
    for (int r = 0; r < 4; ++r)
      rsum[r] = s[0][r] + s[1][r] + s[2][r] + s[3][r];
#pragma unroll
    for (int off = 1; off < 16; off <<= 1)
#pragma unroll
      for (int r = 0; r < 4; ++r)
        rsum[r] += __shfl_xor(rsum[r], off);
#pragma unroll
    for (int r = 0; r < 4; ++r) {
      l_r[r] = l_r[r] * sc[r] + rsum[r];
      m_r[r] = mnew[r];
    }
#pragma unroll
    for (int c = 0; c < 4; ++c)
#pragma unroll
      for (int r = 0; r < 4; ++r)
        acc[c][r] *= sc[r];
    // P -> LDS (bf16) in A-operand layout, then PV
#pragma unroll
    for (int j16 = 0; j16 < 4; ++j16)
#pragma unroll
      for (int r = 0; r < 4; ++r)
        Plds[w][g * 4 + r][j16 * 16 + l15] = (bf16_t)s[j16][r];

    bf16x8 pf[2];
    pf[0] = *(const bf16x8*)&Plds[w][l15][g * 8];
    pf[1] = *(const bf16x8*)&Plds[w][l15][32 + g * 8];
#pragma unroll
    for (int c = 0; c < 4; ++c) {
      const bf16_t* vp = &Vt[(size_t)(h * 64 + c * 16 + l15) * T_DIM + kb + g * 8];
      acc[c] = __builtin_amdgcn_mfma_f32_16x16x32_bf16(pf[0], *(const bf16x8*)vp,        acc[c], 0, 0, 0);
      acc[c] = __builtin_amdgcn_mfma_f32_16x16x32_bf16(pf[1], *(const bf16x8*)(vp + 32), acc[c], 0, 0, 0);
    }
  }

  // epilogue: O = acc / l
#pragma unroll
  for (int c = 0; c < 4; ++c)
#pragma unroll
    for (int r = 0; r < 4; ++r) {
      float o = acc[c][r] / l_r[r];
      Oattn[(size_t)(qrow + g * 4 + r) * E_DIM + h * 64 + c * 16 + l15] = (bf16_t)o;
    }
}

extern "C" void kernel_launch(void* const* d_in, const int* in_sizes, int n_in,
                              void* d_out, int out_size, void* d_ws, size_t ws_size,
                              hipStream_t stream) {
  const float* q  = (const float*)d_in[0];
  const float* k  = (const float*)d_in[1];
  const float* v  = (const float*)d_in[2];
  const float* Wq = (const float*)d_in[3];
  const float* Wk = (const float*)d_in[4];
  const float* Wv = (const float*)d_in[5];
  const float* Wo = (const float*)d_in[6];
  float* out = (float*)d_out;

  const size_t TE = (size_t)T_DIM * E_DIM;
  bf16_t* Qp = (bf16_t*)d_ws;
  bf16_t* Kp = Qp + TE;
  bf16_t* Vt = Kp + TE;   // [E][T]
  bf16_t* Oa = Vt + TE;   // [T][E]

  dim3 blk(256);
  // Qp = q @ Wq^T   (M=T, N=E, K=E)
  gemm_bt<float, float, bf16_t><<<dim3(E_DIM / 128, T_DIM / 128), blk, 0, stream>>>(q, Wq, Qp, T_DIM, E_DIM, E_DIM);
  // Kp = k @ Wk^T
  gemm_bt<float, float, bf16_t><<<dim3(E_DIM / 128, T_DIM / 128), blk, 0, stream>>>(k, Wk, Kp, T_DIM, E_DIM, E_DIM);
  // Vt = Wv @ v^T   (M=E, N=T, K=E)  -> V projection, pre-transposed [E][T]
  gemm_bt<float, float, bf16_t><<<dim3(T_DIM / 128, E_DIM / 128), blk, 0, stream>>>(Wv, v, Vt, E_DIM, T_DIM, E_DIM);
  // attention
  attn_fwd<<<dim3(T_DIM / 64, H_DIM), blk, 0, stream>>>(Qp, Kp, Vt, Oa);
  // out = Oa @ Wo^T (fp32 out)
  gemm_bt<bf16_t, float, float><<<dim3(E_DIM / 128, T_DIM / 128), blk, 0, stream>>>(Oa, Wo, out, T_DIM, E_DIM, E_DIM);
}

// Round 2
// 299.993 us; speedup vs baseline: 1.9515x; 1.9515x over previous
//
#include <hip/hip_runtime.h>
#include <hip/hip_bf16.h>

// Problem constants (B=1)
#define T_DIM 4096
#define E_DIM 1024
#define H_DIM 16
#define HD_DIM 64
#define SCALE_F 0.125f   // 8.0 / HD

typedef __bf16 bf16_t;
typedef __bf16 bf16x8 __attribute__((ext_vector_type(8)));
typedef float  f32x4  __attribute__((ext_vector_type(4)));

// ---- staging helpers: load 8 elements, convert to bf16, 16B LDS write ----
__device__ inline void stage8(bf16_t* dst, const float* src) {
  const f32x4* s4 = (const f32x4*)src;
  f32x4 a = s4[0], b = s4[1];
  bf16x8 o;
  o[0] = (bf16_t)a[0]; o[1] = (bf16_t)a[1]; o[2] = (bf16_t)a[2]; o[3] = (bf16_t)a[3];
  o[4] = (bf16_t)b[0]; o[5] = (bf16_t)b[1]; o[6] = (bf16_t)b[2]; o[7] = (bf16_t)b[3];
  *(bf16x8*)dst = o;
}
__device__ inline void stage8(bf16_t* dst, const bf16_t* src) {
  *(bf16x8*)dst = *(const bf16x8*)src;
}

// ---- GEMM: C[M][N] = A[M][K] x B[N][K]^T (both row-major, K contiguous) ----
template <typename TA, typename TB, typename TC>
__global__ __launch_bounds__(256) void gemm_bt(const TA* __restrict__ A,
                                               const TB* __restrict__ B,
                                               TC* __restrict__ C,
                                               int M, int N, int K) {
  __shared__ alignas(16) bf16_t As[128][40];
  __shared__ alignas(16) bf16_t Bs[128][40];
  const int tid  = threadIdx.x;
  const int lane = tid & 63, w = tid >> 6;
  const int g = lane >> 4, l15 = lane & 15;
  const int wr = w >> 1, wc = w & 1;
  const int bm = blockIdx.y * 128, bn = blockIdx.x * 128;

  f32x4 acc[4][4] = {};

  for (int kt = 0; kt < K; kt += 32) {
    __syncthreads();
#pragma unroll
    for (int i = 0; i < 2; ++i) {
      int v   = tid + i * 256;
      int row = v >> 2, c8 = (v & 3) * 8;
      stage8(&As[row][c8], &A[(size_t)(bm + row) * K + kt + c8]);
      stage8(&Bs[row][c8], &B[(size_t)(bn + row) * K + kt + c8]);
    }
    __syncthreads();

    bf16x8 af[4], bfr[4];
#pragma unroll
    for (int m = 0; m < 4; ++m)
      af[m] = *(const bf16x8*)&As[wr * 64 + m * 16 + l15][g * 8];
#pragma unroll
    for (int n = 0; n < 4; ++n)
      bfr[n] = *(const bf16x8*)&Bs[wc * 64 + n * 16 + l15][g * 8];
#pragma unroll
    for (int m = 0; m < 4; ++m)
#pragma unroll
      for (int n = 0; n < 4; ++n)
        acc[m][n] = __builtin_amdgcn_mfma_f32_16x16x32_bf16(af[m], bfr[n], acc[m][n], 0, 0, 0);
  }

#pragma unroll
  for (int m = 0; m < 4; ++m)
#pragma unroll
    for (int n = 0; n < 4; ++n)
#pragma unroll
      for (int r = 0; r < 4; ++r) {
        int row = bm + wr * 64 + m * 16 + g * 4 + r;
        int col = bn + wc * 64 + n * 16 + l15;
        C[(size_t)row * N + col] = (TC)acc[m][n][r];
      }
}

// ---- attention helpers ----
__device__ inline void gld_lds16(const bf16_t* g, bf16_t* l) {
  __builtin_amdgcn_global_load_lds(
      (const __attribute__((address_space(1))) unsigned int*)g,
      (__attribute__((address_space(3))) unsigned int*)l, 16, 0, 0);
}

// Stage a 64x64 bf16 tile (global row stride = gstride elems) into LDS,
// XOR-swizzled: within-row 16B chunk c of row r lands at chunk c ^ (r&7).
// global_load_lds dest stays linear (base + lane*16); the swizzle is applied
// to the per-lane GLOBAL source address (m173 pattern).
__device__ inline void stage_tile64(const bf16_t* gbase, size_t gstride,
                                    bf16_t* lds, int tid) {
#pragma unroll
  for (int p = 0; p < 2; ++p) {
    int s = p * 256 + tid;          // 512 slots of 16B
    int row = s >> 3, l8 = s & 7;
    int cg = l8 ^ (row & 7);
    gld_lds16(gbase + (size_t)row * gstride + cg * 8, lds + s * 8);
  }
}

// DPP rotation reduce across 16-lane rows (full-rate VALU, no LDS latency)
template <int CTRL>
__device__ inline float dpp_rot(float x) {
  return __builtin_bit_cast(float,
      __builtin_amdgcn_update_dpp(0, __builtin_bit_cast(int, x), CTRL, 0xF, 0xF, true));
}
__device__ inline float red_max16(float x) {
  x = fmaxf(x, dpp_rot<0x121>(x));  // row_ror:1
  x = fmaxf(x, dpp_rot<0x122>(x));  // row_ror:2
  x = fmaxf(x, dpp_rot<0x124>(x));  // row_ror:4
  x = fmaxf(x, dpp_rot<0x128>(x));  // row_ror:8
  return x;
}
__device__ inline float red_sum16(float x) {
  x += dpp_rot<0x121>(x);
  x += dpp_rot<0x122>(x);
  x += dpp_rot<0x124>(x);
  x += dpp_rot<0x128>(x);
  return x;
}

// ---- Flash attention, causal, online softmax ----
// grid (T/64, H), 256 threads (4 waves). Wave w owns Q rows qt+w*16..+16.
// K/V tiles double-buffered in LDS (shared by all 4 waves), prefetched 1 ahead.
__global__ __launch_bounds__(256) void attn_fwd(const bf16_t* __restrict__ Qp,
                                                const bf16_t* __restrict__ Kp,
                                                const bf16_t* __restrict__ Vt,
                                                bf16_t* __restrict__ Oattn) {
  const int h  = blockIdx.y;
  const int qi = (T_DIM / 64 - 1) - blockIdx.x;  // big blocks first
  const int tid = threadIdx.x, lane = tid & 63, w = tid >> 6;
  const int g = lane >> 4, l15 = lane & 15;
  const int qt = qi * 64;
  const int qrow = qt + w * 16;

  __shared__ alignas(16) bf16_t Ks[2][64][64];   // swizzled, 8 KB each
  __shared__ alignas(16) bf16_t Vs[2][64][64];
  __shared__ alignas(16) bf16_t Plds[4][16][72]; // per-wave P, padded

  bf16x8 qf[2];
  {
    const bf16_t* qp = &Qp[(size_t)(qrow + l15) * E_DIM + h * 64 + g * 8];
    qf[0] = *(const bf16x8*)qp;
    qf[1] = *(const bf16x8*)(qp + 32);
  }

  f32x4 acc[4] = {};
  float m_r[4], l_r[4];
#pragma unroll
  for (int r = 0; r < 4; ++r) { m_r[r] = -1e30f; l_r[r] = 0.f; }

  int buf = 0;
  // prologue: stage tile 0
  stage_tile64(Kp + (size_t)0 * E_DIM + h * 64, E_DIM, &Ks[0][0][0], tid);
  stage_tile64(Vt + (size_t)(h * 64) * T_DIM + 0, T_DIM, &Vs[0][0][0], tid);

  for (int j = 0; j <= qi; ++j) {
    const int kb = j * 64;
    asm volatile("s_waitcnt vmcnt(0)" ::: "memory");
    __syncthreads();   // (A) tile j resident for all waves
    if (j < qi) {      // prefetch tile j+1 into the other buffer
      const int kb2 = kb + 64;
      stage_tile64(Kp + (size_t)kb2 * E_DIM + h * 64, E_DIM, &Ks[buf ^ 1][0][0], tid);
      stage_tile64(Vt + (size_t)(h * 64) * T_DIM + kb2, T_DIM, &Vs[buf ^ 1][0][0], tid);
    }

    const char* Kb = (const char*)&Ks[buf][0][0];
    const char* Vb = (const char*)&Vs[buf][0][0];

    // S = Q K^T  (wave: 16 rows x 64 cols)
    f32x4 s[4] = {};
#pragma unroll
    for (int j16 = 0; j16 < 4; ++j16) {
      const int r0 = j16 * 16 + l15;
      const char* rp = Kb + r0 * 128;
      const int sw = (r0 & 7) << 4;
      bf16x8 k0 = *(const bf16x8*)(rp + ((g * 16) ^ sw));
      bf16x8 k1 = *(const bf16x8*)(rp + ((64 + g * 16) ^ sw));
      s[j16] = __builtin_amdgcn_mfma_f32_16x16x32_bf16(qf[0], k0, s[j16], 0, 0, 0);
      s[j16] = __builtin_amdgcn_mfma_f32_16x16x32_bf16(qf[1], k1, s[j16], 0, 0, 0);
    }

    // scale + causal mask (only diagonal tile needs masking)
    const bool diag = (j == qi);
#pragma unroll
    for (int j16 = 0; j16 < 4; ++j16)
#pragma unroll
      for (int r = 0; r < 4; ++r) {
        float sv = s[j16][r] * SCALE_F;
        if (diag && (kb + j16 * 16 + l15 > qrow + g * 4 + r)) sv = -1e30f;
        s[j16][r] = sv;
      }

    // online softmax (per 16-lane group; DPP rotation reduce)
    float rmax[4], mnew[4], sc[4], rsum[4];
#pragma unroll
    for (int r = 0; r < 4; ++r) {
      rmax[r] = red_max16(fmaxf(fmaxf(s[0][r], s[1][r]), fmaxf(s[2][r], s[3][r])));
      mnew[r] = fmaxf(m_r[r], rmax[r]);
      sc[r]   = __expf(m_r[r] - mnew[r]);
    }
#pragma unroll
    for (int j16 = 0; j16 < 4; ++j16)
#pragma unroll
      for (int r = 0; r < 4; ++r)
        s[j16][r] = __expf(s[j16][r] - mnew[r]);
#pragma unroll
    for (int r = 0; r < 4; ++r) {
      rsum[r] = red_sum16(s[0][r] + s[1][r] + s[2][r] + s[3][r]);
      l_r[r] = l_r[r] * sc[r] + rsum[r];
      m_r[r] = mnew[r];
    }

    // P -> LDS (bf16) in A-operand layout
#pragma unroll
    for (int j16 = 0; j16 < 4; ++j16)
#pragma unroll
      for (int r = 0; r < 4; ++r)
        Plds[w][g * 4 + r][j16 * 16 + l15] = (bf16_t)s[j16][r];

    // rescale accumulator (overlaps with Plds write latency)
#pragma unroll
    for (int c = 0; c < 4; ++c)
#pragma unroll
      for (int r = 0; r < 4; ++r)
        acc[c][r] *= sc[r];

    bf16x8 pf[2];
    pf[0] = *(const bf16x8*)&Plds[w][l15][g * 8];
    pf[1] = *(const bf16x8*)&Plds[w][l15][32 + g * 8];

    // PV from swizzled LDS V tile
#pragma unroll
    for (int c = 0; c < 4; ++c) {
      const int vr = c * 16 + l15;
      const char* rp = Vb + vr * 128;
      const int sw = (vr & 7) << 4;
      bf16x8 v0 = *(const bf16x8*)(rp + ((g * 16) ^ sw));
      bf16x8 v1 = *(const bf16x8*)(rp + ((64 + g * 16) ^ sw));
      acc[c] = __builtin_amdgcn_mfma_f32_16x16x32_bf16(pf[0], v0, acc[c], 0, 0, 0);
      acc[c] = __builtin_amdgcn_mfma_f32_16x16x32_bf16(pf[1], v1, acc[c], 0, 0, 0);
    }

    __syncthreads();   // (B) all waves done reading buf
    buf ^= 1;
  }

  // epilogue: O = acc / l
#pragma unroll
  for (int c = 0; c < 4; ++c)
#pragma unroll
    for (int r = 0; r < 4; ++r) {
      float o = acc[c][r] / l_r[r];
      Oattn[(size_t)(qrow + g * 4 + r) * E_DIM + h * 64 + c * 16 + l15] = (bf16_t)o;
    }
}

extern "C" void kernel_launch(void* const* d_in, const int* in_sizes, int n_in,
                              void* d_out, int out_size, void* d_ws, size_t ws_size,
                              hipStream_t stream) {
  const float* q  = (const float*)d_in[0];
  const float* k  = (const float*)d_in[1];
  const float* v  = (const float*)d_in[2];
  const float* Wq = (const float*)d_in[3];
  const float* Wk = (const float*)d_in[4];
  const float* Wv = (const float*)d_in[5];
  const float* Wo = (const float*)d_in[6];
  float* out = (float*)d_out;

  const size_t TE = (size_t)T_DIM * E_DIM;
  bf16_t* Qp = (bf16_t*)d_ws;
  bf16_t* Kp = Qp + TE;
  bf16_t* Vt = Kp + TE;   // [E][T]
  bf16_t* Oa = Vt + TE;   // [T][E]

  dim3 blk(256);
  gemm_bt<float, float, bf16_t><<<dim3(E_DIM / 128, T_DIM / 128), blk, 0, stream>>>(q, Wq, Qp, T_DIM, E_DIM, E_DIM);
  gemm_bt<float, float, bf16_t><<<dim3(E_DIM / 128, T_DIM / 128), blk, 0, stream>>>(k, Wk, Kp, T_DIM, E_DIM, E_DIM);
  gemm_bt<float, float, bf16_t><<<dim3(T_DIM / 128, E_DIM / 128), blk, 0, stream>>>(Wv, v, Vt, E_DIM, T_DIM, E_DIM);
  attn_fwd<<<dim3(T_DIM / 64, H_DIM), blk, 0, stream>>>(Qp, Kp, Vt, Oa);
  gemm_bt<bf16_t, float, float><<<dim3(E_DIM / 128, T_DIM / 128), blk, 0, stream>>>(Oa, Wo, out, T_DIM, E_DIM, E_DIM);
}

// Round 3
// 245.123 us; speedup vs baseline: 2.3883x; 1.2238x over previous
//
#include <hip/hip_runtime.h>
#include <hip/hip_bf16.h>

// Problem constants (B=1)
#define T_DIM 4096
#define E_DIM 1024
#define H_DIM 16
#define HD_DIM 64
#define LOG2E_F 1.4426950408889634f
#define QSCALE_F (0.125f * LOG2E_F)   // SCALE * log2(e), folded into Qp

typedef __bf16 bf16_t;
typedef __bf16 bf16x8 __attribute__((ext_vector_type(8)));
typedef float  f32x4  __attribute__((ext_vector_type(4)));

// ---- helpers ----
__device__ inline void stage8(bf16_t* dst, const float* src) {
  const f32x4* s4 = (const f32x4*)src;
  f32x4 a = s4[0], b = s4[1];
  bf16x8 o;
  o[0] = (bf16_t)a[0]; o[1] = (bf16_t)a[1]; o[2] = (bf16_t)a[2]; o[3] = (bf16_t)a[3];
  o[4] = (bf16_t)b[0]; o[5] = (bf16_t)b[1]; o[6] = (bf16_t)b[2]; o[7] = (bf16_t)b[3];
  *(bf16x8*)dst = o;
}
__device__ inline void stage8(bf16_t* dst, const bf16_t* src) {
  *(bf16x8*)dst = *(const bf16x8*)src;
}

__device__ inline void gld_lds16(const bf16_t* g, bf16_t* l) {
  __builtin_amdgcn_global_load_lds(
      (const __attribute__((address_space(1))) unsigned int*)g,
      (__attribute__((address_space(3))) unsigned int*)l, 16, 0, 0);
}

__device__ inline float fexp2(float x) {  // raw v_exp_f32 (exp2)
  float r;
  asm("v_exp_f32 %0, %1" : "=v"(r) : "v"(x));
  return r;
}

// ---- fp32 -> bf16 conversion for all 7 inputs (one launch) ----
__global__ __launch_bounds__(256) void cvt_all(
    const float* __restrict__ q, const float* __restrict__ k, const float* __restrict__ v,
    const float* __restrict__ Wq, const float* __restrict__ Wk,
    const float* __restrict__ Wv, const float* __restrict__ Wo,
    bf16_t* qb, bf16_t* kb, bf16_t* vb,
    bf16_t* Wqb, bf16_t* Wkb, bf16_t* Wvb, bf16_t* Wob) {
  // unit = 8 elems. q/k/v: 524288 units each; W*: 131072 units each.
  for (int u = blockIdx.x * 256 + threadIdx.x; u < 2097152; u += gridDim.x * 256) {
    const float* s; bf16_t* d; int i;
    if (u < 1572864) {
      int seg = u >> 19, off = u & 524287;
      s = seg == 0 ? q : (seg == 1 ? k : v);
      d = seg == 0 ? qb : (seg == 1 ? kb : vb);
      i = off;
    } else {
      int w = u - 1572864;
      int seg = w >> 17, off = w & 131071;
      s = seg == 0 ? Wq : seg == 1 ? Wk : seg == 2 ? Wv : Wo;
      d = seg == 0 ? Wqb : seg == 1 ? Wkb : seg == 2 ? Wvb : Wob;
      i = off;
    }
    stage8(d + (size_t)i * 8, s + (size_t)i * 8);
  }
}

// ---- bf16 GEMM, m97 structure: C[M][N] = (A[M][K] x B[N][K]^T) * cscale ----
// 128x128 tile, BK=64, 256 threads (4 waves 2x2). global_load_lds width=16,
// source-XOR-swizzled (chunk c of row r at c^(r&7)) -> conflict-free b128 reads.
template <typename TC>
__global__ __launch_bounds__(256) void gemm_bt_bf16(const bf16_t* __restrict__ A,
                                                    const bf16_t* __restrict__ B,
                                                    TC* __restrict__ C,
                                                    int M, int N, int K, float cscale) {
  __shared__ alignas(16) bf16_t As[128][64];
  __shared__ alignas(16) bf16_t Bs[128][64];
  const int tid  = threadIdx.x;
  const int lane = tid & 63, w = tid >> 6;
  const int g = lane >> 4, l15 = lane & 15;
  const int wr = w >> 1, wc = w & 1;
  const int bm = blockIdx.y * 128, bn = blockIdx.x * 128;
  if (bm >= M || bn >= N) return;

  f32x4 acc[4][4] = {};

  for (int kt = 0; kt < K; kt += 64) {
    if (kt) __syncthreads();          // all waves done reading prev tile
#pragma unroll
    for (int p = 0; p < 4; ++p) {     // 1024 slots of 16B per tile
      int s = p * 256 + tid;
      int row = s >> 3, c = s & 7;
      int cg = c ^ (row & 7);         // source-side swizzle
      gld_lds16(&A[(size_t)(bm + row) * K + kt + cg * 8], &As[0][0] + s * 8);
      gld_lds16(&B[(size_t)(bn + row) * K + kt + cg * 8], &Bs[0][0] + s * 8);
    }
    asm volatile("s_waitcnt vmcnt(0)" ::: "memory");
    __syncthreads();

#pragma unroll
    for (int hh = 0; hh < 2; ++hh) {  // two K=32 halves
      bf16x8 af[4], bfr[4];
#pragma unroll
      for (int m = 0; m < 4; ++m) {
        int row = wr * 64 + m * 16 + l15;
        af[m] = *(const bf16x8*)(&As[0][0] + row * 64 + (((hh * 4 + g) ^ (row & 7)) * 8));
      }
#pragma unroll
      for (int n = 0; n < 4; ++n) {
        int row = wc * 64 + n * 16 + l15;
        bfr[n] = *(const bf16x8*)(&Bs[0][0] + row * 64 + (((hh * 4 + g) ^ (row & 7)) * 8));
      }
#pragma unroll
      for (int m = 0; m < 4; ++m)
#pragma unroll
        for (int n = 0; n < 4; ++n)
          acc[m][n] = __builtin_amdgcn_mfma_f32_16x16x32_bf16(af[m], bfr[n], acc[m][n], 0, 0, 0);
    }
  }

#pragma unroll
  for (int m = 0; m < 4; ++m)
#pragma unroll
    for (int n = 0; n < 4; ++n)
#pragma unroll
      for (int r = 0; r < 4; ++r) {
        int row = bm + wr * 64 + m * 16 + g * 4 + r;
        int col = bn + wc * 64 + n * 16 + l15;
        C[(size_t)row * N + col] = (TC)(acc[m][n][r] * cscale);
      }
}

// ---- fallback GEMM (fp32 staging, used only if ws too small) ----
template <typename TA, typename TB, typename TC>
__global__ __launch_bounds__(256) void gemm_bt(const TA* __restrict__ A,
                                               const TB* __restrict__ B,
                                               TC* __restrict__ C,
                                               int M, int N, int K, float cscale) {
  __shared__ alignas(16) bf16_t As[128][40];
  __shared__ alignas(16) bf16_t Bs[128][40];
  const int tid  = threadIdx.x;
  const int lane = tid & 63, w = tid >> 6;
  const int g = lane >> 4, l15 = lane & 15;
  const int wr = w >> 1, wc = w & 1;
  const int bm = blockIdx.y * 128, bn = blockIdx.x * 128;

  f32x4 acc[4][4] = {};

  for (int kt = 0; kt < K; kt += 32) {
    __syncthreads();
#pragma unroll
    for (int i = 0; i < 2; ++i) {
      int vv  = tid + i * 256;
      int row = vv >> 2, c8 = (vv & 3) * 8;
      stage8(&As[row][c8], &A[(size_t)(bm + row) * K + kt + c8]);
      stage8(&Bs[row][c8], &B[(size_t)(bn + row) * K + kt + c8]);
    }
    __syncthreads();

    bf16x8 af[4], bfr[4];
#pragma unroll
    for (int m = 0; m < 4; ++m)
      af[m] = *(const bf16x8*)&As[wr * 64 + m * 16 + l15][g * 8];
#pragma unroll
    for (int n = 0; n < 4; ++n)
      bfr[n] = *(const bf16x8*)&Bs[wc * 64 + n * 16 + l15][g * 8];
#pragma unroll
    for (int m = 0; m < 4; ++m)
#pragma unroll
      for (int n = 0; n < 4; ++n)
        acc[m][n] = __builtin_amdgcn_mfma_f32_16x16x32_bf16(af[m], bfr[n], acc[m][n], 0, 0, 0);
  }

#pragma unroll
  for (int m = 0; m < 4; ++m)
#pragma unroll
    for (int n = 0; n < 4; ++n)
#pragma unroll
      for (int r = 0; r < 4; ++r) {
        int row = bm + wr * 64 + m * 16 + g * 4 + r;
        int col = bn + wc * 64 + n * 16 + l15;
        C[(size_t)row * N + col] = (TC)(acc[m][n][r] * cscale);
      }
}

// ---- DPP rotation reduce across 16-lane rows ----
template <int CTRL>
__device__ inline float dpp_rot(float x) {
  return __builtin_bit_cast(float,
      __builtin_amdgcn_update_dpp(0, __builtin_bit_cast(int, x), CTRL, 0xF, 0xF, true));
}
__device__ inline float red_max16(float x) {
  x = fmaxf(x, dpp_rot<0x121>(x));
  x = fmaxf(x, dpp_rot<0x122>(x));
  x = fmaxf(x, dpp_rot<0x124>(x));
  x = fmaxf(x, dpp_rot<0x128>(x));
  return x;
}
__device__ inline float red_sum16(float x) {
  x += dpp_rot<0x121>(x);
  x += dpp_rot<0x122>(x);
  x += dpp_rot<0x124>(x);
  x += dpp_rot<0x128>(x);
  return x;
}

// ---- Flash attention, causal, online softmax (log2 domain, pre-scaled Q) ----
__global__ __launch_bounds__(256) void attn_fwd(const bf16_t* __restrict__ Qp,
                                                const bf16_t* __restrict__ Kp,
                                                const bf16_t* __restrict__ Vt,
                                                bf16_t* __restrict__ Oattn) {
  const int h  = blockIdx.y;
  const int qi = (T_DIM / 64 - 1) - blockIdx.x;  // big blocks first
  const int tid = threadIdx.x, lane = tid & 63, w = tid >> 6;
  const int g = lane >> 4, l15 = lane & 15;
  const int qrow = qi * 64 + w * 16;

  __shared__ alignas(16) bf16_t Ks[2][64][64];   // swizzled, 8 KB each
  __shared__ alignas(16) bf16_t Vs[2][64][64];
  __shared__ alignas(16) bf16_t Plds[4][16][72];

  bf16x8 qf[2];
  {
    const bf16_t* qp = &Qp[(size_t)(qrow + l15) * E_DIM + h * 64 + g * 8];
    qf[0] = *(const bf16x8*)qp;
    qf[1] = *(const bf16x8*)(qp + 32);
  }

  // hoisted staging pointers (2 K-slots + 2 V-slots per thread)
  const int sA = tid, sB = 256 + tid;
  const int rA = sA >> 3, cA = ((sA & 7) ^ (rA & 7)) * 8;
  const int rB = sB >> 3, cB = ((sB & 7) ^ (rB & 7)) * 8;
  const bf16_t* srcK0 = Kp + (size_t)rA * E_DIM + h * 64 + cA;
  const bf16_t* srcK1 = Kp + (size_t)rB * E_DIM + h * 64 + cB;
  const bf16_t* srcV0 = Vt + (size_t)(h * 64 + rA) * T_DIM + cA;
  const bf16_t* srcV1 = Vt + (size_t)(h * 64 + rB) * T_DIM + cB;
  bf16_t* dK0 = &Ks[0][0][0] + sA * 8;
  bf16_t* dK1 = &Ks[0][0][0] + sB * 8;
  bf16_t* dV0 = &Vs[0][0][0] + sA * 8;
  bf16_t* dV1 = &Vs[0][0][0] + sB * 8;
  const size_t BUFO = 64 * 64;          // elems per buffer
  const size_t KADV = (size_t)64 * E_DIM;

  f32x4 acc[4] = {};
  float m_r[4], l_r[4];
#pragma unroll
  for (int r = 0; r < 4; ++r) { m_r[r] = -1e30f; l_r[r] = 0.f; }

  int buf = 0;
  // prologue: stage tile 0
  gld_lds16(srcK0, dK0); gld_lds16(srcK1, dK1); srcK0 += KADV; srcK1 += KADV;
  gld_lds16(srcV0, dV0); gld_lds16(srcV1, dV1); srcV0 += 64;   srcV1 += 64;

  for (int j = 0; j <= qi; ++j) {
    const int kb = j * 64;
    asm volatile("s_waitcnt vmcnt(0)" ::: "memory");
    __syncthreads();
    if (j < qi) {
      size_t bo = (buf ^ 1) * BUFO;
      gld_lds16(srcK0, dK0 + bo); gld_lds16(srcK1, dK1 + bo); srcK0 += KADV; srcK1 += KADV;
      gld_lds16(srcV0, dV0 + bo); gld_lds16(srcV1, dV1 + bo); srcV0 += 64;   srcV1 += 64;
    }

    const char* Kb = (const char*)&Ks[buf][0][0];
    const char* Vb = (const char*)&Vs[buf][0][0];

    // S' = (Q*SCALE*log2e) K^T   (wave: 16 rows x 64 cols)
    f32x4 s[4] = {};
    __builtin_amdgcn_s_setprio(1);
#pragma unroll
    for (int j16 = 0; j16 < 4; ++j16) {
      const int r0 = j16 * 16 + l15;
      const char* rp = Kb + r0 * 128;
      const int sw = (r0 & 7) << 4;
      bf16x8 k0 = *(const bf16x8*)(rp + ((g * 16) ^ sw));
      bf16x8 k1 = *(const bf16x8*)(rp + ((64 + g * 16) ^ sw));
      s[j16] = __builtin_amdgcn_mfma_f32_16x16x32_bf16(qf[0], k0, s[j16], 0, 0, 0);
      s[j16] = __builtin_amdgcn_mfma_f32_16x16x32_bf16(qf[1], k1, s[j16], 0, 0, 0);
    }
    __builtin_amdgcn_s_setprio(0);

    // causal mask (diagonal tile only)
    if (j == qi) {
#pragma unroll
      for (int j16 = 0; j16 < 4; ++j16)
#pragma unroll
        for (int r = 0; r < 4; ++r)
          if (kb + j16 * 16 + l15 > qrow + g * 4 + r) s[j16][r] = -1e30f;
    }

    // online softmax in log2 domain, defer-rescale (THR=11 log2-units)
    float rmax[4];
#pragma unroll
    for (int r = 0; r < 4; ++r)
      rmax[r] = red_max16(fmaxf(fmaxf(s[0][r], s[1][r]), fmaxf(s[2][r], s[3][r])));

    int stable = 1;
#pragma unroll
    for (int r = 0; r < 4; ++r) stable &= (rmax[r] <= m_r[r] + 11.0f);
    if (!__all(stable)) {
#pragma unroll
      for (int r = 0; r < 4; ++r) {
        float mn = fmaxf(m_r[r], rmax[r]);
        float sc = fexp2(m_r[r] - mn);
        m_r[r] = mn;
        l_r[r] *= sc;
#pragma unroll
        for (int c = 0; c < 4; ++c) acc[c][r] *= sc;
      }
    }

#pragma unroll
    for (int j16 = 0; j16 < 4; ++j16)
#pragma unroll
      for (int r = 0; r < 4; ++r)
        s[j16][r] = fexp2(s[j16][r] - m_r[r]);

    float rsum[4];
#pragma unroll
    for (int r = 0; r < 4; ++r) {
      rsum[r] = red_sum16(s[0][r] + s[1][r] + s[2][r] + s[3][r]);
      l_r[r] += rsum[r];
    }

    // P -> LDS (bf16) in A-operand layout
#pragma unroll
    for (int j16 = 0; j16 < 4; ++j16)
#pragma unroll
      for (int r = 0; r < 4; ++r)
        Plds[w][g * 4 + r][j16 * 16 + l15] = (bf16_t)s[j16][r];

    bf16x8 pf[2];
    pf[0] = *(const bf16x8*)&Plds[w][l15][g * 8];
    pf[1] = *(const bf16x8*)&Plds[w][l15][32 + g * 8];

    __builtin_amdgcn_s_setprio(1);
#pragma unroll
    for (int c = 0; c < 4; ++c) {
      const int vr = c * 16 + l15;
      const char* rp = Vb + vr * 128;
      const int sw = (vr & 7) << 4;
      bf16x8 v0 = *(const bf16x8*)(rp + ((g * 16) ^ sw));
      bf16x8 v1 = *(const bf16x8*)(rp + ((64 + g * 16) ^ sw));
      acc[c] = __builtin_amdgcn_mfma_f32_16x16x32_bf16(pf[0], v0, acc[c], 0, 0, 0);
      acc[c] = __builtin_amdgcn_mfma_f32_16x16x32_bf16(pf[1], v1, acc[c], 0, 0, 0);
    }
    __builtin_amdgcn_s_setprio(0);

    __syncthreads();
    buf ^= 1;
  }

#pragma unroll
  for (int c = 0; c < 4; ++c)
#pragma unroll
    for (int r = 0; r < 4; ++r) {
      float o = acc[c][r] / l_r[r];
      Oattn[(size_t)(qrow + g * 4 + r) * E_DIM + h * 64 + c * 16 + l15] = (bf16_t)o;
    }
}

extern "C" void kernel_launch(void* const* d_in, const int* in_sizes, int n_in,
                              void* d_out, int out_size, void* d_ws, size_t ws_size,
                              hipStream_t stream) {
  const float* q  = (const float*)d_in[0];
  const float* k  = (const float*)d_in[1];
  const float* v  = (const float*)d_in[2];
  const float* Wq = (const float*)d_in[3];
  const float* Wk = (const float*)d_in[4];
  const float* Wv = (const float*)d_in[5];
  const float* Wo = (const float*)d_in[6];
  float* out = (float*)d_out;

  const size_t TE = (size_t)T_DIM * E_DIM;   // 4M elems
  const size_t EE = (size_t)E_DIM * E_DIM;   // 1M elems
  dim3 blk(256);

  if (ws_size >= (size_t)56 * 1024 * 1024) {
    // fast path: bf16 inputs + global_load_lds GEMMs
    bf16_t* qb  = (bf16_t*)d_ws;          // reused as Oa after projections
    bf16_t* kb  = qb + TE;
    bf16_t* vb  = kb + TE;
    bf16_t* Wqb = vb + TE;
    bf16_t* Wkb = Wqb + EE;
    bf16_t* Wvb = Wkb + EE;
    bf16_t* Wob = Wvb + EE;
    bf16_t* Qp  = Wob + EE;
    bf16_t* Kp  = Qp + TE;
    bf16_t* Vt  = Kp + TE;                // [E][T]
    bf16_t* Oa  = qb;                     // alias

    cvt_all<<<2048, blk, 0, stream>>>(q, k, v, Wq, Wk, Wv, Wo,
                                      qb, kb, vb, Wqb, Wkb, Wvb, Wob);
    gemm_bt_bf16<bf16_t><<<dim3(8, 32), blk, 0, stream>>>(qb, Wqb, Qp, T_DIM, E_DIM, E_DIM, QSCALE_F);
    gemm_bt_bf16<bf16_t><<<dim3(8, 32), blk, 0, stream>>>(kb, Wkb, Kp, T_DIM, E_DIM, E_DIM, 1.0f);
    gemm_bt_bf16<bf16_t><<<dim3(32, 8), blk, 0, stream>>>(Wvb, vb, Vt, E_DIM, T_DIM, E_DIM, 1.0f);
    attn_fwd<<<dim3(T_DIM / 64, H_DIM), blk, 0, stream>>>(Qp, Kp, Vt, Oa);
    gemm_bt_bf16<float><<<dim3(8, 32), blk, 0, stream>>>(Oa, Wob, out, T_DIM, E_DIM, E_DIM, 1.0f);
  } else {
    // fallback: fp32-staging GEMMs (32 MB ws)
    bf16_t* Qp = (bf16_t*)d_ws;
    bf16_t* Kp = Qp + TE;
    bf16_t* Vt = Kp + TE;
    bf16_t* Oa = Vt + TE;
    gemm_bt<float, float, bf16_t><<<dim3(8, 32), blk, 0, stream>>>(q, Wq, Qp, T_DIM, E_DIM, E_DIM, QSCALE_F);
    gemm_bt<float, float, bf16_t><<<dim3(8, 32), blk, 0, stream>>>(k, Wk, Kp, T_DIM, E_DIM, E_DIM, 1.0f);
    gemm_bt<float, float, bf16_t><<<dim3(32, 8), blk, 0, stream>>>(Wv, v, Vt, E_DIM, T_DIM, E_DIM, 1.0f);
    attn_fwd<<<dim3(T_DIM / 64, H_DIM), blk, 0, stream>>>(Qp, Kp, Vt, Oa);
    gemm_bt<bf16_t, float, float><<<dim3(8, 32), blk, 0, stream>>>(Oa, Wo, out, T_DIM, E_DIM, E_DIM, 1.0f);
  }
}

// Round 5
// 233.813 us; speedup vs baseline: 2.5038x; 1.0484x over previous
//
#include <hip/hip_runtime.h>
#include <hip/hip_bf16.h>

// Problem constants (B=1)
#define T_DIM 4096
#define E_DIM 1024
#define H_DIM 16
#define HD_DIM 64
#define LOG2E_F 1.4426950408889634f
#define QSCALE_F (0.125f * LOG2E_F)   // SCALE * log2(e), folded into Qp

typedef __bf16 bf16_t;
typedef __bf16 bf16x8 __attribute__((ext_vector_type(8)));
typedef float  f32x4  __attribute__((ext_vector_type(4)));

// ---- helpers ----
__device__ inline void stage8(bf16_t* dst, const float* src) {
  const f32x4* s4 = (const f32x4*)src;
  f32x4 a = s4[0], b = s4[1];
  bf16x8 o;
  o[0] = (bf16_t)a[0]; o[1] = (bf16_t)a[1]; o[2] = (bf16_t)a[2]; o[3] = (bf16_t)a[3];
  o[4] = (bf16_t)b[0]; o[5] = (bf16_t)b[1]; o[6] = (bf16_t)b[2]; o[7] = (bf16_t)b[3];
  *(bf16x8*)dst = o;
}
__device__ inline void stage8(bf16_t* dst, const bf16_t* src) {
  *(bf16x8*)dst = *(const bf16x8*)src;
}

__device__ inline void gld_lds16(const bf16_t* g, bf16_t* l) {
  __builtin_amdgcn_global_load_lds(
      (const __attribute__((address_space(1))) unsigned int*)g,
      (__attribute__((address_space(3))) unsigned int*)l, 16, 0, 0);
}

__device__ inline float fexp2(float x) {  // raw v_exp_f32 (exp2)
  float r;
  asm("v_exp_f32 %0, %1" : "=v"(r) : "v"(x));
  return r;
}

// raw barrier (no implicit vmcnt(0) drain) + compiler memory fence
__device__ inline void block_sync() {
  asm volatile("" ::: "memory");
  __builtin_amdgcn_s_barrier();
  asm volatile("" ::: "memory");
}

// ---- fp32 -> bf16 conversion for all 7 inputs (one launch) ----
__global__ __launch_bounds__(256) void cvt_all(
    const float* __restrict__ q, const float* __restrict__ k, const float* __restrict__ v,
    const float* __restrict__ Wq, const float* __restrict__ Wk,
    const float* __restrict__ Wv, const float* __restrict__ Wo,
    bf16_t* qb, bf16_t* kb, bf16_t* vb,
    bf16_t* Wqb, bf16_t* Wkb, bf16_t* Wvb, bf16_t* Wob) {
  for (int u = blockIdx.x * 256 + threadIdx.x; u < 2097152; u += gridDim.x * 256) {
    const float* s; bf16_t* d; int i;
    if (u < 1572864) {
      int seg = u >> 19, off = u & 524287;
      s = seg == 0 ? q : (seg == 1 ? k : v);
      d = seg == 0 ? qb : (seg == 1 ? kb : vb);
      i = off;
    } else {
      int w = u - 1572864;
      int seg = w >> 17, off = w & 131071;
      s = seg == 0 ? Wq : seg == 1 ? Wk : seg == 2 ? Wv : Wo;
      d = seg == 0 ? Wqb : seg == 1 ? Wkb : seg == 2 ? Wvb : Wob;
      i = off;
    }
    stage8(d + (size_t)i * 8, s + (size_t)i * 8);
  }
}

// ---- bf16 GEMM, m97 structure: C[M][N] = (A[M][K] x B[N][K]^T) * cscale ----
template <typename TC>
__global__ __launch_bounds__(256) void gemm_bt_bf16(const bf16_t* __restrict__ A,
                                                    const bf16_t* __restrict__ B,
                                                    TC* __restrict__ C,
                                                    int M, int N, int K, float cscale) {
  __shared__ alignas(16) bf16_t As[128][64];
  __shared__ alignas(16) bf16_t Bs[128][64];
  const int tid  = threadIdx.x;
  const int lane = tid & 63, w = tid >> 6;
  const int g = lane >> 4, l15 = lane & 15;
  const int wr = w >> 1, wc = w & 1;
  const int bm = blockIdx.y * 128, bn = blockIdx.x * 128;
  if (bm >= M || bn >= N) return;

  f32x4 acc[4][4] = {};

  for (int kt = 0; kt < K; kt += 64) {
    if (kt) __syncthreads();
#pragma unroll
    for (int p = 0; p < 4; ++p) {
      int s = p * 256 + tid;
      int row = s >> 3, c = s & 7;
      int cg = c ^ (row & 7);
      gld_lds16(&A[(size_t)(bm + row) * K + kt + cg * 8], &As[0][0] + s * 8);
      gld_lds16(&B[(size_t)(bn + row) * K + kt + cg * 8], &Bs[0][0] + s * 8);
    }
    asm volatile("s_waitcnt vmcnt(0)" ::: "memory");
    __syncthreads();

#pragma unroll
    for (int hh = 0; hh < 2; ++hh) {
      bf16x8 af[4], bfr[4];
#pragma unroll
      for (int m = 0; m < 4; ++m) {
        int row = wr * 64 + m * 16 + l15;
        af[m] = *(const bf16x8*)(&As[0][0] + row * 64 + (((hh * 4 + g) ^ (row & 7)) * 8));
      }
#pragma unroll
      for (int n = 0; n < 4; ++n) {
        int row = wc * 64 + n * 16 + l15;
        bfr[n] = *(const bf16x8*)(&Bs[0][0] + row * 64 + (((hh * 4 + g) ^ (row & 7)) * 8));
      }
#pragma unroll
      for (int m = 0; m < 4; ++m)
#pragma unroll
        for (int n = 0; n < 4; ++n)
          acc[m][n] = __builtin_amdgcn_mfma_f32_16x16x32_bf16(af[m], bfr[n], acc[m][n], 0, 0, 0);
    }
  }

#pragma unroll
  for (int m = 0; m < 4; ++m)
#pragma unroll
    for (int n = 0; n < 4; ++n)
#pragma unroll
      for (int r = 0; r < 4; ++r) {
        int row = bm + wr * 64 + m * 16 + g * 4 + r;
        int col = bn + wc * 64 + n * 16 + l15;
        C[(size_t)row * N + col] = (TC)(acc[m][n][r] * cscale);
      }
}

// ---- fallback GEMM (fp32 staging, used only if ws too small) ----
template <typename TA, typename TB, typename TC>
__global__ __launch_bounds__(256) void gemm_bt(const TA* __restrict__ A,
                                               const TB* __restrict__ B,
                                               TC* __restrict__ C,
                                               int M, int N, int K, float cscale) {
  __shared__ alignas(16) bf16_t As[128][40];
  __shared__ alignas(16) bf16_t Bs[128][40];
  const int tid  = threadIdx.x;
  const int lane = tid & 63, w = tid >> 6;
  const int g = lane >> 4, l15 = lane & 15;
  const int wr = w >> 1, wc = w & 1;
  const int bm = blockIdx.y * 128, bn = blockIdx.x * 128;

  f32x4 acc[4][4] = {};

  for (int kt = 0; kt < K; kt += 32) {
    __syncthreads();
#pragma unroll
    for (int i = 0; i < 2; ++i) {
      int vv  = tid + i * 256;
      int row = vv >> 2, c8 = (vv & 3) * 8;
      stage8(&As[row][c8], &A[(size_t)(bm + row) * K + kt + c8]);
      stage8(&Bs[row][c8], &B[(size_t)(bn + row) * K + kt + c8]);
    }
    __syncthreads();

    bf16x8 af[4], bfr[4];
#pragma unroll
    for (int m = 0; m < 4; ++m)
      af[m] = *(const bf16x8*)&As[wr * 64 + m * 16 + l15][g * 8];
#pragma unroll
    for (int n = 0; n < 4; ++n)
      bfr[n] = *(const bf16x8*)&Bs[wc * 64 + n * 16 + l15][g * 8];
#pragma unroll
    for (int m = 0; m < 4; ++m)
#pragma unroll
      for (int n = 0; n < 4; ++n)
        acc[m][n] = __builtin_amdgcn_mfma_f32_16x16x32_bf16(af[m], bfr[n], acc[m][n], 0, 0, 0);
  }

#pragma unroll
  for (int m = 0; m < 4; ++m)
#pragma unroll
    for (int n = 0; n < 4; ++n)
#pragma unroll
      for (int r = 0; r < 4; ++r) {
        int row = bm + wr * 64 + m * 16 + g * 4 + r;
        int col = bn + wc * 64 + n * 16 + l15;
        C[(size_t)row * N + col] = (TC)(acc[m][n][r] * cscale);
      }
}

// ---- DPP rotation reduce across 16-lane rows ----
template <int CTRL>
__device__ inline float dpp_rot(float x) {
  return __builtin_bit_cast(float,
      __builtin_amdgcn_update_dpp(0, __builtin_bit_cast(int, x), CTRL, 0xF, 0xF, true));
}
__device__ inline float red_max16(float x) {
  x = fmaxf(x, dpp_rot<0x121>(x));
  x = fmaxf(x, dpp_rot<0x122>(x));
  x = fmaxf(x, dpp_rot<0x124>(x));
  x = fmaxf(x, dpp_rot<0x128>(x));
  return x;
}
__device__ inline float red_sum16(float x) {
  x += dpp_rot<0x121>(x);
  x += dpp_rot<0x122>(x);
  x += dpp_rot<0x124>(x);
  x += dpp_rot<0x128>(x);
  return x;
}

// ---- Flash attention, causal, online softmax (log2 domain, pre-scaled Q) ----
// QBLK=128, 8 waves (512 thr). Wave w owns Q rows qi*128+w*16..+15.
// K/V 64-kv tiles double-buffered in LDS, shared by all 8 waves.
// Counted vmcnt + raw s_barrier: loads stay in flight across phases (T3/T4).
__global__ __launch_bounds__(512) void attn_fwd(const bf16_t* __restrict__ Qp,
                                                const bf16_t* __restrict__ Kp,
                                                const bf16_t* __restrict__ Vt,
                                                bf16_t* __restrict__ Oattn) {
  const int h  = blockIdx.y;
  const int qi = (T_DIM / 128 - 1) - blockIdx.x;  // big blocks first
  const int tid = threadIdx.x, lane = tid & 63, w = tid >> 6;
  const int g = lane >> 4, l15 = lane & 15;
  const int qrow = qi * 128 + w * 16;

  __shared__ alignas(16) bf16_t Ks[2][64][64];   // swizzled, 8 KB each
  __shared__ alignas(16) bf16_t Vs[2][64][64];
  __shared__ alignas(16) bf16_t Plds[8][16][72];

  bf16x8 qf[2];
  {
    const bf16_t* qp = &Qp[(size_t)(qrow + l15) * E_DIM + h * 64 + g * 8];
    qf[0] = *(const bf16x8*)qp;
    qf[1] = *(const bf16x8*)(qp + 32);
  }

  // staging: 512 threads x 16B = one 64x64 tile per (K,V) pass
  const int srow = tid >> 3, sc = tid & 7;
  const int scg = (sc ^ (srow & 7)) * 8;           // source-side swizzle
  const bf16_t* srcK = Kp + (size_t)srow * E_DIM + h * 64 + scg;
  const bf16_t* srcV = Vt + (size_t)(h * 64 + srow) * T_DIM + scg;
  bf16_t* dK = &Ks[0][0][0] + tid * 8;
  bf16_t* dV = &Vs[0][0][0] + tid * 8;
  const size_t BUFO = 64 * 64;
  const size_t KADV = (size_t)64 * E_DIM;
  const int nt = 2 * qi + 2;

  f32x4 acc[4] = {};
  float m_r[4], l_r[4];
#pragma unroll
  for (int r = 0; r < 4; ++r) { m_r[r] = -1e30f; l_r[r] = 0.f; }

  int buf = 0;
  // prologue: stage tile 0 (K first, then V — vmcnt counting relies on order)
  gld_lds16(srcK, dK); srcK += KADV;
  gld_lds16(srcV, dV); srcV += 64;

  for (int j = 0; j < nt; ++j) {
    const int kb = j * 64;
    // K_j landed (V_j may still be in flight)
    asm volatile("s_waitcnt vmcnt(1)" ::: "memory");
    block_sync();                         // all waves confirmed their K_j
    if (j + 1 < nt) {                     // issue next tile immediately
      size_t bo = (size_t)(buf ^ 1) * BUFO;
      gld_lds16(srcK, dK + bo); srcK += KADV;
      gld_lds16(srcV, dV + bo); srcV += 64;
    }

    const char* Kb = (const char*)&Ks[buf][0][0];
    const char* Vb = (const char*)&Vs[buf][0][0];

    // S' = (Q*SCALE*log2e) K^T   (wave: 16 rows x 64 cols)
    f32x4 s[4] = {};
    __builtin_amdgcn_s_setprio(1);
#pragma unroll
    for (int j16 = 0; j16 < 4; ++j16) {
      const int r0 = j16 * 16 + l15;
      const char* rp = Kb + r0 * 128;
      const int sw = (r0 & 7) << 4;
      bf16x8 k0 = *(const bf16x8*)(rp + ((g * 16) ^ sw));
      bf16x8 k1 = *(const bf16x8*)(rp + ((64 + g * 16) ^ sw));
      s[j16] = __builtin_amdgcn_mfma_f32_16x16x32_bf16(qf[0], k0, s[j16], 0, 0, 0);
      s[j16] = __builtin_amdgcn_mfma_f32_16x16x32_bf16(qf[1], k1, s[j16], 0, 0, 0);
    }
    __builtin_amdgcn_s_setprio(0);

    // causal mask: needed whenever any element of the tile has kv > q.
    // min q row in this wave is qrow  ==>  mask iff kb+63 > qrow.
    // (Round-4 bug: used qrow+15, which skipped masking for qrow == kb+48.)
    if (kb + 63 > qrow) {
#pragma unroll
      for (int j16 = 0; j16 < 4; ++j16)
#pragma unroll
        for (int r = 0; r < 4; ++r)
          if (kb + j16 * 16 + l15 > qrow + g * 4 + r) s[j16][r] = -1e30f;
    }

    // online softmax in log2 domain, defer-rescale (THR=11 log2-units)
    float rmax[4];
#pragma unroll
    for (int r = 0; r < 4; ++r)
      rmax[r] = red_max16(fmaxf(fmaxf(s[0][r], s[1][r]), fmaxf(s[2][r], s[3][r])));

    int stable = 1;
#pragma unroll
    for (int r = 0; r < 4; ++r) stable &= (rmax[r] <= m_r[r] + 11.0f);
    if (!__all(stable)) {
#pragma unroll
      for (int r = 0; r < 4; ++r) {
        float mn = fmaxf(m_r[r], rmax[r]);
        float sc = fexp2(m_r[r] - mn);
        m_r[r] = mn;
        l_r[r] *= sc;
#pragma unroll
        for (int c = 0; c < 4; ++c) acc[c][r] *= sc;
      }
    }

#pragma unroll
    for (int j16 = 0; j16 < 4; ++j16)
#pragma unroll
      for (int r = 0; r < 4; ++r)
        s[j16][r] = fexp2(s[j16][r] - m_r[r]);

    float rsum[4];
#pragma unroll
    for (int r = 0; r < 4; ++r) {
      rsum[r] = red_sum16(s[0][r] + s[1][r] + s[2][r] + s[3][r]);
      l_r[r] += rsum[r];
    }

    // P -> LDS (bf16) in A-operand layout (per-wave buffer, same-wave reads)
#pragma unroll
    for (int j16 = 0; j16 < 4; ++j16)
#pragma unroll
      for (int r = 0; r < 4; ++r)
        Plds[w][g * 4 + r][j16 * 16 + l15] = (bf16_t)s[j16][r];

    // V_j landed (next tile's K/V may still be in flight)
    if (j + 1 < nt) { asm volatile("s_waitcnt vmcnt(2)" ::: "memory"); }
    else            { asm volatile("s_waitcnt vmcnt(0)" ::: "memory"); }
    block_sync();                         // all waves confirmed their V_j

    bf16x8 pf[2];
    pf[0] = *(const bf16x8*)&Plds[w][l15][g * 8];
    pf[1] = *(const bf16x8*)&Plds[w][l15][32 + g * 8];

    __builtin_amdgcn_s_setprio(1);
#pragma unroll
    for (int c = 0; c < 4; ++c) {
      const int vr = c * 16 + l15;
      const char* rp = Vb + vr * 128;
      const int sw = (vr & 7) << 4;
      bf16x8 v0 = *(const bf16x8*)(rp + ((g * 16) ^ sw));
      bf16x8 v1 = *(const bf16x8*)(rp + ((64 + g * 16) ^ sw));
      acc[c] = __builtin_amdgcn_mfma_f32_16x16x32_bf16(pf[0], v0, acc[c], 0, 0, 0);
      acc[c] = __builtin_amdgcn_mfma_f32_16x16x32_bf16(pf[1], v1, acc[c], 0, 0, 0);
    }
    __builtin_amdgcn_s_setprio(0);

    buf ^= 1;
  }

#pragma unroll
  for (int c = 0; c < 4; ++c)
#pragma unroll
    for (int r = 0; r < 4; ++r) {
      float o = acc[c][r] / l_r[r];
      Oattn[(size_t)(qrow + g * 4 + r) * E_DIM + h * 64 + c * 16 + l15] = (bf16_t)o;
    }
}

extern "C" void kernel_launch(void* const* d_in, const int* in_sizes, int n_in,
                              void* d_out, int out_size, void* d_ws, size_t ws_size,
                              hipStream_t stream) {
  const float* q  = (const float*)d_in[0];
  const float* k  = (const float*)d_in[1];
  const float* v  = (const float*)d_in[2];
  const float* Wq = (const float*)d_in[3];
  const float* Wk = (const float*)d_in[4];
  const float* Wv = (const float*)d_in[5];
  const float* Wo = (const float*)d_in[6];
  float* out = (float*)d_out;

  const size_t TE = (size_t)T_DIM * E_DIM;   // 4M elems
  const size_t EE = (size_t)E_DIM * E_DIM;   // 1M elems
  dim3 blk(256);

  if (ws_size >= (size_t)56 * 1024 * 1024) {
    bf16_t* qb  = (bf16_t*)d_ws;          // reused as Oa after projections
    bf16_t* kb  = qb + TE;
    bf16_t* vb  = kb + TE;
    bf16_t* Wqb = vb + TE;
    bf16_t* Wkb = Wqb + EE;
    bf16_t* Wvb = Wkb + EE;
    bf16_t* Wob = Wvb + EE;
    bf16_t* Qp  = Wob + EE;
    bf16_t* Kp  = Qp + TE;
    bf16_t* Vt  = Kp + TE;                // [E][T]
    bf16_t* Oa  = qb;                     // alias

    cvt_all<<<2048, blk, 0, stream>>>(q, k, v, Wq, Wk, Wv, Wo,
                                      qb, kb, vb, Wqb, Wkb, Wvb, Wob);
    gemm_bt_bf16<bf16_t><<<dim3(8, 32), blk, 0, stream>>>(qb, Wqb, Qp, T_DIM, E_DIM, E_DIM, QSCALE_F);
    gemm_bt_bf16<bf16_t><<<dim3(8, 32), blk, 0, stream>>>(kb, Wkb, Kp, T_DIM, E_DIM, E_DIM, 1.0f);
    gemm_bt_bf16<bf16_t><<<dim3(32, 8), blk, 0, stream>>>(Wvb, vb, Vt, E_DIM, T_DIM, E_DIM, 1.0f);
    attn_fwd<<<dim3(T_DIM / 128, H_DIM), dim3(512), 0, stream>>>(Qp, Kp, Vt, Oa);
    gemm_bt_bf16<float><<<dim3(8, 32), blk, 0, stream>>>(Oa, Wob, out, T_DIM, E_DIM, E_DIM, 1.0f);
  } else {
    bf16_t* Qp = (bf16_t*)d_ws;
    bf16_t* Kp = Qp + TE;
    bf16_t* Vt = Kp + TE;
    bf16_t* Oa = Vt + TE;
    gemm_bt<float, float, bf16_t><<<dim3(8, 32), blk, 0, stream>>>(q, Wq, Qp, T_DIM, E_DIM, E_DIM, QSCALE_F);
    gemm_bt<float, float, bf16_t><<<dim3(8, 32), blk, 0, stream>>>(k, Wk, Kp, T_DIM, E_DIM, E_DIM, 1.0f);
    gemm_bt<float, float, bf16_t><<<dim3(32, 8), blk, 0, stream>>>(Wv, v, Vt, E_DIM, T_DIM, E_DIM, 1.0f);
    attn_fwd<<<dim3(T_DIM / 128, H_DIM), dim3(512), 0, stream>>>(Qp, Kp, Vt, Oa);
    gemm_bt<bf16_t, float, float><<<dim3(8, 32), blk, 0, stream>>>(Oa, Wo, out, T_DIM, E_DIM, E_DIM, 1.0f);
  }
}

// Round 6
// 199.598 us; speedup vs baseline: 2.9330x; 1.1714x over previous
//
#include <hip/hip_runtime.h>
#include <hip/hip_bf16.h>

// Problem constants (B=1)
#define T_DIM 4096
#define E_DIM 1024
#define H_DIM 16
#define HD_DIM 64
#define LOG2E_F 1.4426950408889634f
#define QSCALE_F (0.125f * LOG2E_F)   // SCALE * log2(e), folded into Qp

typedef __bf16 bf16_t;
typedef __bf16 bf16x8 __attribute__((ext_vector_type(8)));
typedef float  f32x4  __attribute__((ext_vector_type(4)));

// ---- helpers ----
__device__ inline void stage8(bf16_t* dst, const float* src) {
  const f32x4* s4 = (const f32x4*)src;
  f32x4 a = s4[0], b = s4[1];
  bf16x8 o;
  o[0] = (bf16_t)a[0]; o[1] = (bf16_t)a[1]; o[2] = (bf16_t)a[2]; o[3] = (bf16_t)a[3];
  o[4] = (bf16_t)b[0]; o[5] = (bf16_t)b[1]; o[6] = (bf16_t)b[2]; o[7] = (bf16_t)b[3];
  *(bf16x8*)dst = o;
}
__device__ inline void stage8(bf16_t* dst, const bf16_t* src) {
  *(bf16x8*)dst = *(const bf16x8*)src;
}

__device__ inline void gld_lds16(const bf16_t* g, bf16_t* l) {
  __builtin_amdgcn_global_load_lds(
      (const __attribute__((address_space(1))) unsigned int*)g,
      (__attribute__((address_space(3))) unsigned int*)l, 16, 0, 0);
}

__device__ inline float fexp2(float x) {  // raw v_exp_f32 (exp2)
  float r;
  asm("v_exp_f32 %0, %1" : "=v"(r) : "v"(x));
  return r;
}

// raw barrier (no implicit vmcnt(0) drain) + compiler memory fence
__device__ inline void block_sync() {
  asm volatile("" ::: "memory");
  __builtin_amdgcn_s_barrier();
  asm volatile("" ::: "memory");
}

// ---- fp32 -> bf16 conversion for all 7 inputs (one launch) ----
__global__ __launch_bounds__(256) void cvt_all(
    const float* __restrict__ q, const float* __restrict__ k, const float* __restrict__ v,
    const float* __restrict__ Wq, const float* __restrict__ Wk,
    const float* __restrict__ Wv, const float* __restrict__ Wo,
    bf16_t* qb, bf16_t* kb, bf16_t* vb,
    bf16_t* Wqb, bf16_t* Wkb, bf16_t* Wvb, bf16_t* Wob) {
  for (int u = blockIdx.x * 256 + threadIdx.x; u < 2097152; u += gridDim.x * 256) {
    const float* s; bf16_t* d; int i;
    if (u < 1572864) {
      int seg = u >> 19, off = u & 524287;
      s = seg == 0 ? q : (seg == 1 ? k : v);
      d = seg == 0 ? qb : (seg == 1 ? kb : vb);
      i = off;
    } else {
      int w = u - 1572864;
      int seg = w >> 17, off = w & 131071;
      s = seg == 0 ? Wq : seg == 1 ? Wk : seg == 2 ? Wv : Wo;
      d = seg == 0 ? Wqb : seg == 1 ? Wkb : seg == 2 ? Wvb : Wob;
      i = off;
    }
    stage8(d + (size_t)i * 8, s + (size_t)i * 8);
  }
}

// ---- bf16 GEMM, m97 structure: C[M][N] = (A[M][K] x B[N][K]^T) * cscale ----
template <typename TC>
__global__ __launch_bounds__(256) void gemm_bt_bf16(const bf16_t* __restrict__ A,
                                                    const bf16_t* __restrict__ B,
                                                    TC* __restrict__ C,
                                                    int M, int N, int K, float cscale) {
  __shared__ alignas(16) bf16_t As[128][64];
  __shared__ alignas(16) bf16_t Bs[128][64];
  const int tid  = threadIdx.x;
  const int lane = tid & 63, w = tid >> 6;
  const int g = lane >> 4, l15 = lane & 15;
  const int wr = w >> 1, wc = w & 1;
  const int bm = blockIdx.y * 128, bn = blockIdx.x * 128;
  if (bm >= M || bn >= N) return;

  f32x4 acc[4][4] = {};

  for (int kt = 0; kt < K; kt += 64) {
    if (kt) __syncthreads();
#pragma unroll
    for (int p = 0; p < 4; ++p) {
      int s = p * 256 + tid;
      int row = s >> 3, c = s & 7;
      int cg = c ^ (row & 7);
      gld_lds16(&A[(size_t)(bm + row) * K + kt + cg * 8], &As[0][0] + s * 8);
      gld_lds16(&B[(size_t)(bn + row) * K + kt + cg * 8], &Bs[0][0] + s * 8);
    }
    asm volatile("s_waitcnt vmcnt(0)" ::: "memory");
    __syncthreads();

#pragma unroll
    for (int hh = 0; hh < 2; ++hh) {
      bf16x8 af[4], bfr[4];
#pragma unroll
      for (int m = 0; m < 4; ++m) {
        int row = wr * 64 + m * 16 + l15;
        af[m] = *(const bf16x8*)(&As[0][0] + row * 64 + (((hh * 4 + g) ^ (row & 7)) * 8));
      }
#pragma unroll
      for (int n = 0; n < 4; ++n) {
        int row = wc * 64 + n * 16 + l15;
        bfr[n] = *(const bf16x8*)(&Bs[0][0] + row * 64 + (((hh * 4 + g) ^ (row & 7)) * 8));
      }
#pragma unroll
      for (int m = 0; m < 4; ++m)
#pragma unroll
        for (int n = 0; n < 4; ++n)
          acc[m][n] = __builtin_amdgcn_mfma_f32_16x16x32_bf16(af[m], bfr[n], acc[m][n], 0, 0, 0);
    }
  }

#pragma unroll
  for (int m = 0; m < 4; ++m)
#pragma unroll
    for (int n = 0; n < 4; ++n)
#pragma unroll
      for (int r = 0; r < 4; ++r) {
        int row = bm + wr * 64 + m * 16 + g * 4 + r;
        int col = bn + wc * 64 + n * 16 + l15;
        C[(size_t)row * N + col] = (TC)(acc[m][n][r] * cscale);
      }
}

// ---- fallback GEMM (fp32 staging, used only if ws too small) ----
template <typename TA, typename TB, typename TC>
__global__ __launch_bounds__(256) void gemm_bt(const TA* __restrict__ A,
                                               const TB* __restrict__ B,
                                               TC* __restrict__ C,
                                               int M, int N, int K, float cscale) {
  __shared__ alignas(16) bf16_t As[128][40];
  __shared__ alignas(16) bf16_t Bs[128][40];
  const int tid  = threadIdx.x;
  const int lane = tid & 63, w = tid >> 6;
  const int g = lane >> 4, l15 = lane & 15;
  const int wr = w >> 1, wc = w & 1;
  const int bm = blockIdx.y * 128, bn = blockIdx.x * 128;

  f32x4 acc[4][4] = {};

  for (int kt = 0; kt < K; kt += 32) {
    __syncthreads();
#pragma unroll
    for (int i = 0; i < 2; ++i) {
      int vv  = tid + i * 256;
      int row = vv >> 2, c8 = (vv & 3) * 8;
      stage8(&As[row][c8], &A[(size_t)(bm + row) * K + kt + c8]);
      stage8(&Bs[row][c8], &B[(size_t)(bn + row) * K + kt + c8]);
    }
    __syncthreads();

    bf16x8 af[4], bfr[4];
#pragma unroll
    for (int m = 0; m < 4; ++m)
      af[m] = *(const bf16x8*)&As[wr * 64 + m * 16 + l15][g * 8];
#pragma unroll
    for (int n = 0; n < 4; ++n)
      bfr[n] = *(const bf16x8*)&Bs[wc * 64 + n * 16 + l15][g * 8];
#pragma unroll
    for (int m = 0; m < 4; ++m)
#pragma unroll
      for (int n = 0; n < 4; ++n)
        acc[m][n] = __builtin_amdgcn_mfma_f32_16x16x32_bf16(af[m], bfr[n], acc[m][n], 0, 0, 0);
  }

#pragma unroll
  for (int m = 0; m < 4; ++m)
#pragma unroll
    for (int n = 0; n < 4; ++n)
#pragma unroll
      for (int r = 0; r < 4; ++r) {
        int row = bm + wr * 64 + m * 16 + g * 4 + r;
        int col = bn + wc * 64 + n * 16 + l15;
        C[(size_t)row * N + col] = (TC)(acc[m][n][r] * cscale);
      }
}

// ---- DPP rotation reduce across 16-lane rows ----
template <int CTRL>
__device__ inline float dpp_rot(float x) {
  return __builtin_bit_cast(float,
      __builtin_amdgcn_update_dpp(0, __builtin_bit_cast(int, x), CTRL, 0xF, 0xF, true));
}
__device__ inline float red_max16(float x) {
  x = fmaxf(x, dpp_rot<0x121>(x));
  x = fmaxf(x, dpp_rot<0x122>(x));
  x = fmaxf(x, dpp_rot<0x124>(x));
  x = fmaxf(x, dpp_rot<0x128>(x));
  return x;
}
__device__ inline float red_sum16(float x) {
  x += dpp_rot<0x121>(x);
  x += dpp_rot<0x122>(x);
  x += dpp_rot<0x124>(x);
  x += dpp_rot<0x128>(x);
  return x;
}

// ---- Flash attention, causal, online softmax (log2 domain, pre-scaled Q) ----
// QBLK=128, 8 waves (512 thr). Wave w owns Q rows qi*128+w*16..+15.
// ONE barrier per KV tile: PV shifted one phase late (PV_{j-1} + QK_j fused
// into one MFMA cluster). K triple-buffered, V quadruple-buffered; issues go
// 2 tiles ahead with uniform vmcnt(2) waits (clamped re-issue keeps counts).
// Balanced bid->(qi,h) map: bid i and i+256 (same CU under round-robin) always
// sum to 68 tiles.
__global__ __launch_bounds__(512) void attn_fwd(const bf16_t* __restrict__ Qp,
                                                const bf16_t* __restrict__ Kp,
                                                const bf16_t* __restrict__ Vt,
                                                bf16_t* __restrict__ Oattn) {
  const int bid = blockIdx.x;
  int qi, h;
  if (bid < 256) { qi = 31 - (bid & 15); h = bid >> 4; }
  else           { qi = (bid - 256) & 15; h = (bid - 256) >> 4; }

  const int tid = threadIdx.x, lane = tid & 63, w = tid >> 6;
  const int g = lane >> 4, l15 = lane & 15;
  const int qrow = qi * 128 + w * 16;

  __shared__ alignas(16) bf16_t Ks[3][64][64];   // swizzled, 8 KB each
  __shared__ alignas(16) bf16_t Vs[4][64][64];
  __shared__ alignas(16) bf16_t Plds[8][16][72];

  bf16x8 qf[2];
  {
    const bf16_t* qp = &Qp[(size_t)(qrow + l15) * E_DIM + h * 64 + g * 8];
    qf[0] = *(const bf16x8*)qp;
    qf[1] = *(const bf16x8*)(qp + 32);
  }

  // staging: 512 threads x 16B = one 64x64 tile per (K,V) pass
  const int srow = tid >> 3, sc = tid & 7;
  const int scg = (sc ^ (srow & 7)) * 8;           // source-side swizzle
  const bf16_t* KpRow = Kp + (size_t)srow * E_DIM + h * 64 + scg;
  const bf16_t* VpRow = Vt + (size_t)(h * 64 + srow) * T_DIM + scg;
  bf16_t* KsAll = &Ks[0][0][0];
  bf16_t* VsAll = &Vs[0][0][0];
  const int nt = 2 * qi + 2;

  auto issue = [&](int t) {   // K first, then V (vmcnt accounting relies on it)
    gld_lds16(KpRow + (size_t)t * (64 * E_DIM), KsAll + (t % 3) * 4096 + tid * 8);
    gld_lds16(VpRow + (size_t)t * 64,           VsAll + (t % 4) * 4096 + tid * 8);
  };

  f32x4 acc[4] = {};
  float m_r[4], l_r[4];
#pragma unroll
  for (int r = 0; r < 4; ++r) { m_r[r] = -1e30f; l_r[r] = 0.f; }

  // prologue: tiles 0 and 1 in flight (nt >= 2 always)
  issue(0);
  issue(1);

  int prev_active = 0;
  for (int j = 0; j < nt; ++j) {
    // own K_j,V_j landed (K_{j+1},V_{j+1} still in flight)
    asm volatile("s_waitcnt vmcnt(2)" ::: "memory");
    block_sync();                       // => ALL waves' K_j,V_j resident; all
                                        //    waves done with phase j-1 compute
    issue(min(j + 2, nt - 1));          // 2-ahead; clamp keeps vmcnt uniform

    const int kb = j * 64;
    const bool active = (kb <= qrow + 15);   // wave-uniform causal skip

    __builtin_amdgcn_s_setprio(1);
    // ---- PV_{j-1} (V slot (j-1)%4; P from Plds written last phase) ----
    if (prev_active) {
      const char* Vb = (const char*)(VsAll + ((j - 1) & 3) * 4096);
      bf16x8 pf0 = *(const bf16x8*)&Plds[w][l15][g * 8];
      bf16x8 pf1 = *(const bf16x8*)&Plds[w][l15][32 + g * 8];
#pragma unroll
      for (int c = 0; c < 4; ++c) {
        const int vr = c * 16 + l15;
        const char* rp = Vb + vr * 128;
        const int sw = (vr & 7) << 4;
        bf16x8 v0 = *(const bf16x8*)(rp + ((g * 16) ^ sw));
        bf16x8 v1 = *(const bf16x8*)(rp + ((64 + g * 16) ^ sw));
        acc[c] = __builtin_amdgcn_mfma_f32_16x16x32_bf16(pf0, v0, acc[c], 0, 0, 0);
        acc[c] = __builtin_amdgcn_mfma_f32_16x16x32_bf16(pf1, v1, acc[c], 0, 0, 0);
      }
    }

    if (active) {
      // ---- S' = (Q*SCALE*log2e) K^T from K slot j%3 ----
      const char* Kb = (const char*)(KsAll + (j % 3) * 4096);
      f32x4 s[4] = {};
#pragma unroll
      for (int j16 = 0; j16 < 4; ++j16) {
        const int r0 = j16 * 16 + l15;
        const char* rp = Kb + r0 * 128;
        const int sw = (r0 & 7) << 4;
        bf16x8 k0 = *(const bf16x8*)(rp + ((g * 16) ^ sw));
        bf16x8 k1 = *(const bf16x8*)(rp + ((64 + g * 16) ^ sw));
        s[j16] = __builtin_amdgcn_mfma_f32_16x16x32_bf16(qf[0], k0, s[j16], 0, 0, 0);
        s[j16] = __builtin_amdgcn_mfma_f32_16x16x32_bf16(qf[1], k1, s[j16], 0, 0, 0);
      }
      __builtin_amdgcn_s_setprio(0);

      // causal mask: needed iff any element has kv > q (min q row = qrow)
      if (kb + 63 > qrow) {
#pragma unroll
        for (int j16 = 0; j16 < 4; ++j16)
#pragma unroll
          for (int r = 0; r < 4; ++r)
            if (kb + j16 * 16 + l15 > qrow + g * 4 + r) s[j16][r] = -1e30f;
      }

      // online softmax in log2 domain, defer-rescale (THR=11 log2-units).
      // NOTE: rescale applies AFTER PV_{j-1} was accumulated -- correct order.
      float rmax[4];
#pragma unroll
      for (int r = 0; r < 4; ++r)
        rmax[r] = red_max16(fmaxf(fmaxf(s[0][r], s[1][r]), fmaxf(s[2][r], s[3][r])));

      int stable = 1;
#pragma unroll
      for (int r = 0; r < 4; ++r) stable &= (rmax[r] <= m_r[r] + 11.0f);
      if (!__all(stable)) {
#pragma unroll
        for (int r = 0; r < 4; ++r) {
          float mn = fmaxf(m_r[r], rmax[r]);
          float sc = fexp2(m_r[r] - mn);
          m_r[r] = mn;
          l_r[r] *= sc;
#pragma unroll
          for (int c = 0; c < 4; ++c) acc[c][r] *= sc;
        }
      }

#pragma unroll
      for (int j16 = 0; j16 < 4; ++j16)
#pragma unroll
        for (int r = 0; r < 4; ++r)
          s[j16][r] = fexp2(s[j16][r] - m_r[r]);

      float rsum[4];
#pragma unroll
      for (int r = 0; r < 4; ++r) {
        rsum[r] = red_sum16(s[0][r] + s[1][r] + s[2][r] + s[3][r]);
        l_r[r] += rsum[r];
      }

      // P -> LDS (bf16) in A-operand layout (per-wave buffer, same-wave use)
#pragma unroll
      for (int j16 = 0; j16 < 4; ++j16)
#pragma unroll
        for (int r = 0; r < 4; ++r)
          Plds[w][g * 4 + r][j16 * 16 + l15] = (bf16_t)s[j16][r];
    } else {
      __builtin_amdgcn_s_setprio(0);
    }
    prev_active = active;
  }

  // epilogue phase: PV for the last tile
  asm volatile("s_waitcnt vmcnt(0)" ::: "memory");
  block_sync();
  if (prev_active) {
    const char* Vb = (const char*)(VsAll + ((nt - 1) & 3) * 4096);
    bf16x8 pf0 = *(const bf16x8*)&Plds[w][l15][g * 8];
    bf16x8 pf1 = *(const bf16x8*)&Plds[w][l15][32 + g * 8];
#pragma unroll
    for (int c = 0; c < 4; ++c) {
      const int vr = c * 16 + l15;
      const char* rp = Vb + vr * 128;
      const int sw = (vr & 7) << 4;
      bf16x8 v0 = *(const bf16x8*)(rp + ((g * 16) ^ sw));
      bf16x8 v1 = *(const bf16x8*)(rp + ((64 + g * 16) ^ sw));
      acc[c] = __builtin_amdgcn_mfma_f32_16x16x32_bf16(pf0, v0, acc[c], 0, 0, 0);
      acc[c] = __builtin_amdgcn_mfma_f32_16x16x32_bf16(pf1, v1, acc[c], 0, 0, 0);
    }
  }

#pragma unroll
  for (int c = 0; c < 4; ++c)
#pragma unroll
    for (int r = 0; r < 4; ++r) {
      float o = acc[c][r] / l_r[r];
      Oattn[(size_t)(qrow + g * 4 + r) * E_DIM + h * 64 + c * 16 + l15] = (bf16_t)o;
    }
}

extern "C" void kernel_launch(void* const* d_in, const int* in_sizes, int n_in,
                              void* d_out, int out_size, void* d_ws, size_t ws_size,
                              hipStream_t stream) {
  const float* q  = (const float*)d_in[0];
  const float* k  = (const float*)d_in[1];
  const float* v  = (const float*)d_in[2];
  const float* Wq = (const float*)d_in[3];
  const float* Wk = (const float*)d_in[4];
  const float* Wv = (const float*)d_in[5];
  const float* Wo = (const float*)d_in[6];
  float* out = (float*)d_out;

  const size_t TE = (size_t)T_DIM * E_DIM;   // 4M elems
  const size_t EE = (size_t)E_DIM * E_DIM;   // 1M elems
  dim3 blk(256);

  if (ws_size >= (size_t)56 * 1024 * 1024) {
    bf16_t* qb  = (bf16_t*)d_ws;          // reused as Oa after projections
    bf16_t* kb  = qb + TE;
    bf16_t* vb  = kb + TE;
    bf16_t* Wqb = vb + TE;
    bf16_t* Wkb = Wqb + EE;
    bf16_t* Wvb = Wkb + EE;
    bf16_t* Wob = Wvb + EE;
    bf16_t* Qp  = Wob + EE;
    bf16_t* Kp  = Qp + TE;
    bf16_t* Vt  = Kp + TE;                // [E][T]
    bf16_t* Oa  = qb;                     // alias

    cvt_all<<<2048, blk, 0, stream>>>(q, k, v, Wq, Wk, Wv, Wo,
                                      qb, kb, vb, Wqb, Wkb, Wvb, Wob);
    gemm_bt_bf16<bf16_t><<<dim3(8, 32), blk, 0, stream>>>(qb, Wqb, Qp, T_DIM, E_DIM, E_DIM, QSCALE_F);
    gemm_bt_bf16<bf16_t><<<dim3(8, 32), blk, 0, stream>>>(kb, Wkb, Kp, T_DIM, E_DIM, E_DIM, 1.0f);
    gemm_bt_bf16<bf16_t><<<dim3(32, 8), blk, 0, stream>>>(Wvb, vb, Vt, E_DIM, T_DIM, E_DIM, 1.0f);
    attn_fwd<<<dim3(512), dim3(512), 0, stream>>>(Qp, Kp, Vt, Oa);
    gemm_bt_bf16<float><<<dim3(8, 32), blk, 0, stream>>>(Oa, Wob, out, T_DIM, E_DIM, E_DIM, 1.0f);
  } else {
    bf16_t* Qp = (bf16_t*)d_ws;
    bf16_t* Kp = Qp + TE;
    bf16_t* Vt = Kp + TE;
    bf16_t* Oa = Vt + TE;
    gemm_bt<float, float, bf16_t><<<dim3(8, 32), blk, 0, stream>>>(q, Wq, Qp, T_DIM, E_DIM, E_DIM, QSCALE_F);
    gemm_bt<float, float, bf16_t><<<dim3(8, 32), blk, 0, stream>>>(k, Wk, Kp, T_DIM, E_DIM, E_DIM, 1.0f);
    gemm_bt<float, float, bf16_t><<<dim3(32, 8), blk, 0, stream>>>(Wv, v, Vt, E_DIM, T_DIM, E_DIM, 1.0f);
    attn_fwd<<<dim3(512), dim3(512), 0, stream>>>(Qp, Kp, Vt, Oa);
    gemm_bt<bf16_t, float, float><<<dim3(8, 32), blk, 0, stream>>>(Oa, Wo, out, T_DIM, E_DIM, E_DIM, 1.0f);
  }
}

// Round 7
// 168.417 us; speedup vs baseline: 3.4760x; 1.1851x over previous
//
#include <hip/hip_runtime.h>
#include <hip/hip_bf16.h>

// Problem constants (B=1)
#define T_DIM 4096
#define E_DIM 1024
#define H_DIM 16
#define HD_DIM 64
#define LOG2E_F 1.4426950408889634f
#define QSCALE_F (0.125f * LOG2E_F)   // SCALE * log2(e), folded into Qp

typedef __bf16 bf16_t;
typedef __bf16 bf16x8 __attribute__((ext_vector_type(8)));
typedef float  f32x4  __attribute__((ext_vector_type(4)));

// ---- helpers ----
__device__ inline void stage8(bf16_t* dst, const float* src) {
  const f32x4* s4 = (const f32x4*)src;
  f32x4 a = s4[0], b = s4[1];
  bf16x8 o;
  o[0] = (bf16_t)a[0]; o[1] = (bf16_t)a[1]; o[2] = (bf16_t)a[2]; o[3] = (bf16_t)a[3];
  o[4] = (bf16_t)b[0]; o[5] = (bf16_t)b[1]; o[6] = (bf16_t)b[2]; o[7] = (bf16_t)b[3];
  *(bf16x8*)dst = o;
}
__device__ inline void stage8(bf16_t* dst, const bf16_t* src) {
  *(bf16x8*)dst = *(const bf16x8*)src;
}

__device__ inline void gld_lds16(const bf16_t* g, bf16_t* l) {
  __builtin_amdgcn_global_load_lds(
      (const __attribute__((address_space(1))) unsigned int*)g,
      (__attribute__((address_space(3))) unsigned int*)l, 16, 0, 0);
}

__device__ inline float fexp2(float x) {  // raw v_exp_f32 (exp2)
  float r;
  asm("v_exp_f32 %0, %1" : "=v"(r) : "v"(x));
  return r;
}

// raw barrier (no implicit vmcnt(0) drain) + compiler memory fence
__device__ inline void block_sync() {
  asm volatile("" ::: "memory");
  __builtin_amdgcn_s_barrier();
  asm volatile("" ::: "memory");
}

// ---- fp32 -> bf16 conversion for all 7 inputs (one launch) ----
__global__ __launch_bounds__(256) void cvt_all(
    const float* __restrict__ q, const float* __restrict__ k, const float* __restrict__ v,
    const float* __restrict__ Wq, const float* __restrict__ Wk,
    const float* __restrict__ Wv, const float* __restrict__ Wo,
    bf16_t* qb, bf16_t* kb, bf16_t* vb,
    bf16_t* Wqb, bf16_t* Wkb, bf16_t* Wvb, bf16_t* Wob) {
  for (int u = blockIdx.x * 256 + threadIdx.x; u < 2097152; u += gridDim.x * 256) {
    const float* s; bf16_t* d; int i;
    if (u < 1572864) {
      int seg = u >> 19, off = u & 524287;
      s = seg == 0 ? q : (seg == 1 ? k : v);
      d = seg == 0 ? qb : (seg == 1 ? kb : vb);
      i = off;
    } else {
      int w = u - 1572864;
      int seg = w >> 17, off = w & 131071;
      s = seg == 0 ? Wq : seg == 1 ? Wk : seg == 2 ? Wv : Wo;
      d = seg == 0 ? Wqb : seg == 1 ? Wkb : seg == 2 ? Wvb : Wob;
      i = off;
    }
    stage8(d + (size_t)i * 8, s + (size_t)i * 8);
  }
}

// ---- bf16 GEMM tile body (m97 structure): C = (A[M][1024] x B[N][1024]^T)*cs
// BM=32*MF, BN=32*NF, 256 threads (4 waves 2x2). global_load_lds width=16,
// source-XOR-swizzled (chunk c of row r at c^(r&7)) -> conflict-free b128 reads.
// K fixed at 1024 (all GEMMs here share it). ldA = ldB = 1024.
template <int MF, int NF, typename TC>
__device__ __forceinline__ void gemm_body(const bf16_t* __restrict__ A,
                                          const bf16_t* __restrict__ B,
                                          TC* __restrict__ C,
                                          int ldC, int bm, int bn, float cs) {
  constexpr int BM = 32 * MF, BN = 32 * NF;
  __shared__ alignas(16) bf16_t As[BM][64];
  __shared__ alignas(16) bf16_t Bs[BN][64];
  const int tid  = threadIdx.x;
  const int lane = tid & 63, w = tid >> 6;
  const int g = lane >> 4, l15 = lane & 15;
  const int wr = w >> 1, wc = w & 1;

  f32x4 acc[MF][NF] = {};

  for (int kt = 0; kt < 1024; kt += 64) {
    if (kt) __syncthreads();
#pragma unroll
    for (int p = 0; p < MF; ++p) {            // A: BM*8 slots of 16B
      int s = p * 256 + tid;
      int row = s >> 3, c = s & 7;
      int cg = c ^ (row & 7);
      gld_lds16(&A[(size_t)(bm + row) * 1024 + kt + cg * 8], &As[0][0] + s * 8);
    }
#pragma unroll
    for (int p = 0; p < NF; ++p) {            // B: BN*8 slots
      int s = p * 256 + tid;
      int row = s >> 3, c = s & 7;
      int cg = c ^ (row & 7);
      gld_lds16(&B[(size_t)(bn + row) * 1024 + kt + cg * 8], &Bs[0][0] + s * 8);
    }
    asm volatile("s_waitcnt vmcnt(0)" ::: "memory");
    __syncthreads();

#pragma unroll
    for (int hh = 0; hh < 2; ++hh) {          // two K=32 halves
      bf16x8 af[MF], bfr[NF];
#pragma unroll
      for (int m = 0; m < MF; ++m) {
        int row = wr * (16 * MF) + m * 16 + l15;
        af[m] = *(const bf16x8*)(&As[0][0] + row * 64 + (((hh * 4 + g) ^ (row & 7)) * 8));
      }
#pragma unroll
      for (int n = 0; n < NF; ++n) {
        int row = wc * (16 * NF) + n * 16 + l15;
        bfr[n] = *(const bf16x8*)(&Bs[0][0] + row * 64 + (((hh * 4 + g) ^ (row & 7)) * 8));
      }
#pragma unroll
      for (int m = 0; m < MF; ++m)
#pragma unroll
        for (int n = 0; n < NF; ++n)
          acc[m][n] = __builtin_amdgcn_mfma_f32_16x16x32_bf16(af[m], bfr[n], acc[m][n], 0, 0, 0);
    }
  }

#pragma unroll
  for (int m = 0; m < MF; ++m)
#pragma unroll
    for (int n = 0; n < NF; ++n)
#pragma unroll
      for (int r = 0; r < 4; ++r) {
        int row = bm + wr * (16 * MF) + m * 16 + g * 4 + r;
        int col = bn + wc * (16 * NF) + n * 16 + l15;
        C[(size_t)row * ldC + col] = (TC)(acc[m][n][r] * cs);
      }
}

// ---- fused Q/K/V projections: one launch, 768 blocks (3 blocks/CU) ----
// blocks [0,256): Qp = q@Wq^T *QSCALE; [256,512): Kp = k@Wk^T;
// [512,768): Vt = Wv@v^T (pre-transposed [E][T]).
__global__ __launch_bounds__(256) void proj_qkv(
    const bf16_t* __restrict__ qb, const bf16_t* __restrict__ kb,
    const bf16_t* __restrict__ vb,
    const bf16_t* __restrict__ Wqb, const bf16_t* __restrict__ Wkb,
    const bf16_t* __restrict__ Wvb,
    bf16_t* Qp, bf16_t* Kp, bf16_t* Vt) {
  const int bid = blockIdx.x;
  const int which = bid >> 8, t = bid & 255;
  const bf16_t *A, *B; bf16_t* C; int ldC, bm, bn; float cs;
  if (which == 0) {
    A = qb;  B = Wqb; C = Qp; ldC = 1024;
    bm = (t >> 3) * 128; bn = (t & 7) * 128; cs = QSCALE_F;
  } else if (which == 1) {
    A = kb;  B = Wkb; C = Kp; ldC = 1024;
    bm = (t >> 3) * 128; bn = (t & 7) * 128; cs = 1.0f;
  } else {
    A = Wvb; B = vb;  C = Vt; ldC = 4096;
    bm = (t >> 5) * 128; bn = (t & 31) * 128; cs = 1.0f;
  }
  gemm_body<4, 4, bf16_t>(A, B, C, ldC, bm, bn, cs);   // single call site
}

// ---- final GEMM: out = Oa @ Wo^T, 64x128 tiles -> grid 8x64 (2 blocks/CU).
// M-split keeps re-read on Wo (2MB, L2-resident), not the 8MB activation.
__global__ __launch_bounds__(256) void gemm_fin(const bf16_t* __restrict__ A,
                                                const bf16_t* __restrict__ B,
                                                float* __restrict__ C) {
  gemm_body<2, 4, float>(A, B, C, 1024, blockIdx.y * 64, blockIdx.x * 128, 1.0f);
}

// ---- fallback GEMM (fp32 staging, used only if ws too small) ----
template <typename TA, typename TB, typename TC>
__global__ __launch_bounds__(256) void gemm_bt(const TA* __restrict__ A,
                                               const TB* __restrict__ B,
                                               TC* __restrict__ C,
                                               int M, int N, int K, float cscale) {
  __shared__ alignas(16) bf16_t As[128][40];
  __shared__ alignas(16) bf16_t Bs[128][40];
  const int tid  = threadIdx.x;
  const int lane = tid & 63, w = tid >> 6;
  const int g = lane >> 4, l15 = lane & 15;
  const int wr = w >> 1, wc = w & 1;
  const int bm = blockIdx.y * 128, bn = blockIdx.x * 128;

  f32x4 acc[4][4] = {};

  for (int kt = 0; kt < K; kt += 32) {
    __syncthreads();
#pragma unroll
    for (int i = 0; i < 2; ++i) {
      int vv  = tid + i * 256;
      int row = vv >> 2, c8 = (vv & 3) * 8;
      stage8(&As[row][c8], &A[(size_t)(bm + row) * K + kt + c8]);
      stage8(&Bs[row][c8], &B[(size_t)(bn + row) * K + kt + c8]);
    }
    __syncthreads();

    bf16x8 af[4], bfr[4];
#pragma unroll
    for (int m = 0; m < 4; ++m)
      af[m] = *(const bf16x8*)&As[wr * 64 + m * 16 + l15][g * 8];
#pragma unroll
    for (int n = 0; n < 4; ++n)
      bfr[n] = *(const bf16x8*)&Bs[wc * 64 + n * 16 + l15][g * 8];
#pragma unroll
    for (int m = 0; m < 4; ++m)
#pragma unroll
      for (int n = 0; n < 4; ++n)
        acc[m][n] = __builtin_amdgcn_mfma_f32_16x16x32_bf16(af[m], bfr[n], acc[m][n], 0, 0, 0);
  }

#pragma unroll
  for (int m = 0; m < 4; ++m)
#pragma unroll
    for (int n = 0; n < 4; ++n)
#pragma unroll
      for (int r = 0; r < 4; ++r) {
        int row = bm + wr * 64 + m * 16 + g * 4 + r;
        int col = bn + wc * 64 + n * 16 + l15;
        C[(size_t)row * N + col] = (TC)(acc[m][n][r] * cscale);
      }
}

// ---- DPP rotation reduce across 16-lane rows ----
template <int CTRL>
__device__ inline float dpp_rot(float x) {
  return __builtin_bit_cast(float,
      __builtin_amdgcn_update_dpp(0, __builtin_bit_cast(int, x), CTRL, 0xF, 0xF, true));
}
__device__ inline float red_max16(float x) {
  x = fmaxf(x, dpp_rot<0x121>(x));
  x = fmaxf(x, dpp_rot<0x122>(x));
  x = fmaxf(x, dpp_rot<0x124>(x));
  x = fmaxf(x, dpp_rot<0x128>(x));
  return x;
}
__device__ inline float red_sum16(float x) {
  x += dpp_rot<0x121>(x);
  x += dpp_rot<0x122>(x);
  x += dpp_rot<0x124>(x);
  x += dpp_rot<0x128>(x);
  return x;
}

// ---- Flash attention, causal, online softmax (log2 domain, pre-scaled Q) ----
// QBLK=128, 8 waves (512 thr). ONE barrier per KV tile; PV shifted one phase
// late. K triple-, V quadruple-buffered; 2-ahead issue, uniform vmcnt(2).
// Balanced bid->(qi,h): bid i and i+256 sum to 68 tiles.
__global__ __launch_bounds__(512) void attn_fwd(const bf16_t* __restrict__ Qp,
                                                const bf16_t* __restrict__ Kp,
                                                const bf16_t* __restrict__ Vt,
                                                bf16_t* __restrict__ Oattn) {
  const int bid = blockIdx.x;
  int qi, h;
  if (bid < 256) { qi = 31 - (bid & 15); h = bid >> 4; }
  else           { qi = (bid - 256) & 15; h = (bid - 256) >> 4; }

  const int tid = threadIdx.x, lane = tid & 63, w = tid >> 6;
  const int g = lane >> 4, l15 = lane & 15;
  const int qrow = qi * 128 + w * 16;

  __shared__ alignas(16) bf16_t Ks[3][64][64];   // swizzled, 8 KB each
  __shared__ alignas(16) bf16_t Vs[4][64][64];
  __shared__ alignas(16) bf16_t Plds[8][16][72];

  bf16x8 qf[2];
  {
    const bf16_t* qp = &Qp[(size_t)(qrow + l15) * E_DIM + h * 64 + g * 8];
    qf[0] = *(const bf16x8*)qp;
    qf[1] = *(const bf16x8*)(qp + 32);
  }

  const int srow = tid >> 3, sc = tid & 7;
  const int scg = (sc ^ (srow & 7)) * 8;           // source-side swizzle
  const bf16_t* KpRow = Kp + (size_t)srow * E_DIM + h * 64 + scg;
  const bf16_t* VpRow = Vt + (size_t)(h * 64 + srow) * T_DIM + scg;
  bf16_t* KsAll = &Ks[0][0][0];
  bf16_t* VsAll = &Vs[0][0][0];
  const int nt = 2 * qi + 2;

  auto issue = [&](int t) {   // K first, then V (vmcnt accounting relies on it)
    gld_lds16(KpRow + (size_t)t * (64 * E_DIM), KsAll + (t % 3) * 4096 + tid * 8);
    gld_lds16(VpRow + (size_t)t * 64,           VsAll + (t % 4) * 4096 + tid * 8);
  };

  f32x4 acc[4] = {};
  float m_r[4], l_r[4];
#pragma unroll
  for (int r = 0; r < 4; ++r) { m_r[r] = -1e30f; l_r[r] = 0.f; }

  issue(0);
  issue(1);

  int prev_active = 0;
  for (int j = 0; j < nt; ++j) {
    asm volatile("s_waitcnt vmcnt(2)" ::: "memory");
    block_sync();
    issue(min(j + 2, nt - 1));          // 2-ahead; clamp keeps vmcnt uniform

    const int kb = j * 64;
    const bool active = (kb <= qrow + 15);   // wave-uniform causal skip

    __builtin_amdgcn_s_setprio(1);
    if (prev_active) {                  // PV_{j-1}
      const char* Vb = (const char*)(VsAll + ((j - 1) & 3) * 4096);
      bf16x8 pf0 = *(const bf16x8*)&Plds[w][l15][g * 8];
      bf16x8 pf1 = *(const bf16x8*)&Plds[w][l15][32 + g * 8];
#pragma unroll
      for (int c = 0; c < 4; ++c) {
        const int vr = c * 16 + l15;
        const char* rp = Vb + vr * 128;
        const int sw = (vr & 7) << 4;
        bf16x8 v0 = *(const bf16x8*)(rp + ((g * 16) ^ sw));
        bf16x8 v1 = *(const bf16x8*)(rp + ((64 + g * 16) ^ sw));
        acc[c] = __builtin_amdgcn_mfma_f32_16x16x32_bf16(pf0, v0, acc[c], 0, 0, 0);
        acc[c] = __builtin_amdgcn_mfma_f32_16x16x32_bf16(pf1, v1, acc[c], 0, 0, 0);
      }
    }

    if (active) {                       // QK_j
      const char* Kb = (const char*)(KsAll + (j % 3) * 4096);
      f32x4 s[4] = {};
#pragma unroll
      for (int j16 = 0; j16 < 4; ++j16) {
        const int r0 = j16 * 16 + l15;
        const char* rp = Kb + r0 * 128;
        const int sw = (r0 & 7) << 4;
        bf16x8 k0 = *(const bf16x8*)(rp + ((g * 16) ^ sw));
        bf16x8 k1 = *(const bf16x8*)(rp + ((64 + g * 16) ^ sw));
        s[j16] = __builtin_amdgcn_mfma_f32_16x16x32_bf16(qf[0], k0, s[j16], 0, 0, 0);
        s[j16] = __builtin_amdgcn_mfma_f32_16x16x32_bf16(qf[1], k1, s[j16], 0, 0, 0);
      }
      __builtin_amdgcn_s_setprio(0);

      if (kb + 63 > qrow) {             // causal mask
#pragma unroll
        for (int j16 = 0; j16 < 4; ++j16)
#pragma unroll
          for (int r = 0; r < 4; ++r)
            if (kb + j16 * 16 + l15 > qrow + g * 4 + r) s[j16][r] = -1e30f;
      }

      float rmax[4];
#pragma unroll
      for (int r = 0; r < 4; ++r)
        rmax[r] = red_max16(fmaxf(fmaxf(s[0][r], s[1][r]), fmaxf(s[2][r], s[3][r])));

      int stable = 1;
#pragma unroll
      for (int r = 0; r < 4; ++r) stable &= (rmax[r] <= m_r[r] + 11.0f);
      if (!__all(stable)) {
#pragma unroll
        for (int r = 0; r < 4; ++r) {
          float mn = fmaxf(m_r[r], rmax[r]);
          float sc = fexp2(m_r[r] - mn);
          m_r[r] = mn;
          l_r[r] *= sc;
#pragma unroll
          for (int c = 0; c < 4; ++c) acc[c][r] *= sc;
        }
      }

#pragma unroll
      for (int j16 = 0; j16 < 4; ++j16)
#pragma unroll
        for (int r = 0; r < 4; ++r)
          s[j16][r] = fexp2(s[j16][r] - m_r[r]);

      float rsum[4];
#pragma unroll
      for (int r = 0; r < 4; ++r) {
        rsum[r] = red_sum16(s[0][r] + s[1][r] + s[2][r] + s[3][r]);
        l_r[r] += rsum[r];
      }

#pragma unroll
      for (int j16 = 0; j16 < 4; ++j16)
#pragma unroll
        for (int r = 0; r < 4; ++r)
          Plds[w][g * 4 + r][j16 * 16 + l15] = (bf16_t)s[j16][r];
    } else {
      __builtin_amdgcn_s_setprio(0);
    }
    prev_active = active;
  }

  // epilogue: PV for the last tile
  asm volatile("s_waitcnt vmcnt(0)" ::: "memory");
  block_sync();
  if (prev_active) {
    const char* Vb = (const char*)(VsAll + ((nt - 1) & 3) * 4096);
    bf16x8 pf0 = *(const bf16x8*)&Plds[w][l15][g * 8];
    bf16x8 pf1 = *(const bf16x8*)&Plds[w][l15][32 + g * 8];
#pragma unroll
    for (int c = 0; c < 4; ++c) {
      const int vr = c * 16 + l15;
      const char* rp = Vb + vr * 128;
      const int sw = (vr & 7) << 4;
      bf16x8 v0 = *(const bf16x8*)(rp + ((g * 16) ^ sw));
      bf16x8 v1 = *(const bf16x8*)(rp + ((64 + g * 16) ^ sw));
      acc[c] = __builtin_amdgcn_mfma_f32_16x16x32_bf16(pf0, v0, acc[c], 0, 0, 0);
      acc[c] = __builtin_amdgcn_mfma_f32_16x16x32_bf16(pf1, v1, acc[c], 0, 0, 0);
    }
  }

#pragma unroll
  for (int c = 0; c < 4; ++c)
#pragma unroll
    for (int r = 0; r < 4; ++r) {
      float o = acc[c][r] / l_r[r];
      Oattn[(size_t)(qrow + g * 4 + r) * E_DIM + h * 64 + c * 16 + l15] = (bf16_t)o;
    }
}

extern "C" void kernel_launch(void* const* d_in, const int* in_sizes, int n_in,
                              void* d_out, int out_size, void* d_ws, size_t ws_size,
                              hipStream_t stream) {
  const float* q  = (const float*)d_in[0];
  const float* k  = (const float*)d_in[1];
  const float* v  = (const float*)d_in[2];
  const float* Wq = (const float*)d_in[3];
  const float* Wk = (const float*)d_in[4];
  const float* Wv = (const float*)d_in[5];
  const float* Wo = (const float*)d_in[6];
  float* out = (float*)d_out;

  const size_t TE = (size_t)T_DIM * E_DIM;   // 4M elems
  const size_t EE = (size_t)E_DIM * E_DIM;   // 1M elems
  dim3 blk(256);

  if (ws_size >= (size_t)56 * 1024 * 1024) {
    bf16_t* qb  = (bf16_t*)d_ws;          // reused as Oa after projections
    bf16_t* kb  = qb + TE;
    bf16_t* vb  = kb + TE;
    bf16_t* Wqb = vb + TE;
    bf16_t* Wkb = Wqb + EE;
    bf16_t* Wvb = Wkb + EE;
    bf16_t* Wob = Wvb + EE;
    bf16_t* Qp  = Wob + EE;
    bf16_t* Kp  = Qp + TE;
    bf16_t* Vt  = Kp + TE;                // [E][T]
    bf16_t* Oa  = qb;                     // alias

    cvt_all<<<2048, blk, 0, stream>>>(q, k, v, Wq, Wk, Wv, Wo,
                                      qb, kb, vb, Wqb, Wkb, Wvb, Wob);
    proj_qkv<<<dim3(768), blk, 0, stream>>>(qb, kb, vb, Wqb, Wkb, Wvb, Qp, Kp, Vt);
    attn_fwd<<<dim3(512), dim3(512), 0, stream>>>(Qp, Kp, Vt, Oa);
    gemm_fin<<<dim3(8, 64), blk, 0, stream>>>(Oa, Wob, out);
  } else {
    bf16_t* Qp = (bf16_t*)d_ws;
    bf16_t* Kp = Qp + TE;
    bf16_t* Vt = Kp + TE;
    bf16_t* Oa = Vt + TE;
    gemm_bt<float, float, bf16_t><<<dim3(8, 32), blk, 0, stream>>>(q, Wq, Qp, T_DIM, E_DIM, E_DIM, QSCALE_F);
    gemm_bt<float, float, bf16_t><<<dim3(8, 32), blk, 0, stream>>>(k, Wk, Kp, T_DIM, E_DIM, E_DIM, 1.0f);
    gemm_bt<float, float, bf16_t><<<dim3(32, 8), blk, 0, stream>>>(Wv, v, Vt, E_DIM, T_DIM, E_DIM, 1.0f);
    attn_fwd<<<dim3(512), dim3(512), 0, stream>>>(Qp, Kp, Vt, Oa);
    gemm_bt<bf16_t, float, float><<<dim3(8, 32), blk, 0, stream>>>(Oa, Wo, out, T_DIM, E_DIM, E_DIM, 1.0f);
  }
}

// Round 8
// 142.399 us; speedup vs baseline: 4.1112x; 1.1827x over previous
//
#include <hip/hip_runtime.h>
#include <hip/hip_bf16.h>

// Problem constants (B=1)
#define T_DIM 4096
#define E_DIM 1024
#define H_DIM 16
#define HD_DIM 64
#define LOG2E_F 1.4426950408889634f
#define QSCALE_F (0.125f * LOG2E_F)   // SCALE * log2(e), folded into Qp

typedef __bf16 bf16_t;
typedef __bf16 bf16x8 __attribute__((ext_vector_type(8)));
typedef float  f32x4  __attribute__((ext_vector_type(4)));

// ---- helpers ----
__device__ inline void stage8(bf16_t* dst, const float* src) {
  const f32x4* s4 = (const f32x4*)src;
  f32x4 a = s4[0], b = s4[1];
  bf16x8 o;
  o[0] = (bf16_t)a[0]; o[1] = (bf16_t)a[1]; o[2] = (bf16_t)a[2]; o[3] = (bf16_t)a[3];
  o[4] = (bf16_t)b[0]; o[5] = (bf16_t)b[1]; o[6] = (bf16_t)b[2]; o[7] = (bf16_t)b[3];
  *(bf16x8*)dst = o;
}
__device__ inline void stage8(bf16_t* dst, const bf16_t* src) {
  *(bf16x8*)dst = *(const bf16x8*)src;
}

__device__ inline void gld_lds16(const bf16_t* g, bf16_t* l) {
  __builtin_amdgcn_global_load_lds(
      (const __attribute__((address_space(1))) unsigned int*)g,
      (__attribute__((address_space(3))) unsigned int*)l, 16, 0, 0);
}

__device__ inline float fexp2(float x) {  // raw v_exp_f32 (exp2)
  float r;
  asm("v_exp_f32 %0, %1" : "=v"(r) : "v"(x));
  return r;
}

// raw barrier (no implicit vmcnt(0) drain) + compiler memory fence
__device__ inline void block_sync() {
  asm volatile("" ::: "memory");
  __builtin_amdgcn_s_barrier();
  asm volatile("" ::: "memory");
}

// ---- fp32 -> bf16 conversion for all 7 inputs (one launch) ----
__global__ __launch_bounds__(256) void cvt_all(
    const float* __restrict__ q, const float* __restrict__ k, const float* __restrict__ v,
    const float* __restrict__ Wq, const float* __restrict__ Wk,
    const float* __restrict__ Wv, const float* __restrict__ Wo,
    bf16_t* qb, bf16_t* kb, bf16_t* vb,
    bf16_t* Wqb, bf16_t* Wkb, bf16_t* Wvb, bf16_t* Wob) {
  for (int u = blockIdx.x * 256 + threadIdx.x; u < 2097152; u += gridDim.x * 256) {
    const float* s; bf16_t* d; int i;
    if (u < 1572864) {
      int seg = u >> 19, off = u & 524287;
      s = seg == 0 ? q : (seg == 1 ? k : v);
      d = seg == 0 ? qb : (seg == 1 ? kb : vb);
      i = off;
    } else {
      int w = u - 1572864;
      int seg = w >> 17, off = w & 131071;
      s = seg == 0 ? Wq : seg == 1 ? Wk : seg == 2 ? Wv : Wo;
      d = seg == 0 ? Wqb : seg == 1 ? Wkb : seg == 2 ? Wvb : Wob;
      i = off;
    }
    stage8(d + (size_t)i * 8, s + (size_t)i * 8);
  }
}

// ---- bf16 GEMM tile body (m97 structure): C = (A[M][1024] x B[N][1024]^T)*cs
template <int MF, int NF, typename TC>
__device__ __forceinline__ void gemm_body(const bf16_t* __restrict__ A,
                                          const bf16_t* __restrict__ B,
                                          TC* __restrict__ C,
                                          int ldC, int bm, int bn, float cs) {
  constexpr int BM = 32 * MF, BN = 32 * NF;
  __shared__ alignas(16) bf16_t As[BM][64];
  __shared__ alignas(16) bf16_t Bs[BN][64];
  const int tid  = threadIdx.x;
  const int lane = tid & 63, w = tid >> 6;
  const int g = lane >> 4, l15 = lane & 15;
  const int wr = w >> 1, wc = w & 1;

  f32x4 acc[MF][NF] = {};

  for (int kt = 0; kt < 1024; kt += 64) {
    if (kt) __syncthreads();
#pragma unroll
    for (int p = 0; p < MF; ++p) {
      int s = p * 256 + tid;
      int row = s >> 3, c = s & 7;
      int cg = c ^ (row & 7);
      gld_lds16(&A[(size_t)(bm + row) * 1024 + kt + cg * 8], &As[0][0] + s * 8);
    }
#pragma unroll
    for (int p = 0; p < NF; ++p) {
      int s = p * 256 + tid;
      int row = s >> 3, c = s & 7;
      int cg = c ^ (row & 7);
      gld_lds16(&B[(size_t)(bn + row) * 1024 + kt + cg * 8], &Bs[0][0] + s * 8);
    }
    asm volatile("s_waitcnt vmcnt(0)" ::: "memory");
    __syncthreads();

#pragma unroll
    for (int hh = 0; hh < 2; ++hh) {
      bf16x8 af[MF], bfr[NF];
#pragma unroll
      for (int m = 0; m < MF; ++m) {
        int row = wr * (16 * MF) + m * 16 + l15;
        af[m] = *(const bf16x8*)(&As[0][0] + row * 64 + (((hh * 4 + g) ^ (row & 7)) * 8));
      }
#pragma unroll
      for (int n = 0; n < NF; ++n) {
        int row = wc * (16 * NF) + n * 16 + l15;
        bfr[n] = *(const bf16x8*)(&Bs[0][0] + row * 64 + (((hh * 4 + g) ^ (row & 7)) * 8));
      }
#pragma unroll
      for (int m = 0; m < MF; ++m)
#pragma unroll
        for (int n = 0; n < NF; ++n)
          acc[m][n] = __builtin_amdgcn_mfma_f32_16x16x32_bf16(af[m], bfr[n], acc[m][n], 0, 0, 0);
    }
  }

#pragma unroll
  for (int m = 0; m < MF; ++m)
#pragma unroll
    for (int n = 0; n < NF; ++n)
#pragma unroll
      for (int r = 0; r < 4; ++r) {
        int row = bm + wr * (16 * MF) + m * 16 + g * 4 + r;
        int col = bn + wc * (16 * NF) + n * 16 + l15;
        C[(size_t)row * ldC + col] = (TC)(acc[m][n][r] * cs);
      }
}

// ---- fused Q/K/V projections: one launch, 768 blocks (3 blocks/CU) ----
__global__ __launch_bounds__(256) void proj_qkv(
    const bf16_t* __restrict__ qb, const bf16_t* __restrict__ kb,
    const bf16_t* __restrict__ vb,
    const bf16_t* __restrict__ Wqb, const bf16_t* __restrict__ Wkb,
    const bf16_t* __restrict__ Wvb,
    bf16_t* Qp, bf16_t* Kp, bf16_t* Vt) {
  const int bid = blockIdx.x;
  const int which = bid >> 8, t = bid & 255;
  const bf16_t *A, *B; bf16_t* C; int ldC, bm, bn; float cs;
  if (which == 0) {
    A = qb;  B = Wqb; C = Qp; ldC = 1024;
    bm = (t >> 3) * 128; bn = (t & 7) * 128; cs = QSCALE_F;
  } else if (which == 1) {
    A = kb;  B = Wkb; C = Kp; ldC = 1024;
    bm = (t >> 3) * 128; bn = (t & 7) * 128; cs = 1.0f;
  } else {
    A = Wvb; B = vb;  C = Vt; ldC = 4096;
    bm = (t >> 5) * 128; bn = (t & 31) * 128; cs = 1.0f;
  }
  gemm_body<4, 4, bf16_t>(A, B, C, ldC, bm, bn, cs);
}

// ---- final GEMM: out = Oa @ Wo^T, 64x128 tiles (grid 8x64, 2 blocks/CU) ----
__global__ __launch_bounds__(256) void gemm_fin(const bf16_t* __restrict__ A,
                                                const bf16_t* __restrict__ B,
                                                float* __restrict__ C) {
  gemm_body<2, 4, float>(A, B, C, 1024, blockIdx.y * 64, blockIdx.x * 128, 1.0f);
}

// ---- fallback GEMM (fp32 staging, used only if ws too small) ----
template <typename TA, typename TB, typename TC>
__global__ __launch_bounds__(256) void gemm_bt(const TA* __restrict__ A,
                                               const TB* __restrict__ B,
                                               TC* __restrict__ C,
                                               int M, int N, int K, float cscale) {
  __shared__ alignas(16) bf16_t As[128][40];
  __shared__ alignas(16) bf16_t Bs[128][40];
  const int tid  = threadIdx.x;
  const int lane = tid & 63, w = tid >> 6;
  const int g = lane >> 4, l15 = lane & 15;
  const int wr = w >> 1, wc = w & 1;
  const int bm = blockIdx.y * 128, bn = blockIdx.x * 128;

  f32x4 acc[4][4] = {};

  for (int kt = 0; kt < K; kt += 32) {
    __syncthreads();
#pragma unroll
    for (int i = 0; i < 2; ++i) {
      int vv  = tid + i * 256;
      int row = vv >> 2, c8 = (vv & 3) * 8;
      stage8(&As[row][c8], &A[(size_t)(bm + row) * K + kt + c8]);
      stage8(&Bs[row][c8], &B[(size_t)(bn + row) * K + kt + c8]);
    }
    __syncthreads();

    bf16x8 af[4], bfr[4];
#pragma unroll
    for (int m = 0; m < 4; ++m)
      af[m] = *(const bf16x8*)&As[wr * 64 + m * 16 + l15][g * 8];
#pragma unroll
    for (int n = 0; n < 4; ++n)
      bfr[n] = *(const bf16x8*)&Bs[wc * 64 + n * 16 + l15][g * 8];
#pragma unroll
    for (int m = 0; m < 4; ++m)
#pragma unroll
      for (int n = 0; n < 4; ++n)
        acc[m][n] = __builtin_amdgcn_mfma_f32_16x16x32_bf16(af[m], bfr[n], acc[m][n], 0, 0, 0);
  }

#pragma unroll
  for (int m = 0; m < 4; ++m)
#pragma unroll
    for (int n = 0; n < 4; ++n)
#pragma unroll
      for (int r = 0; r < 4; ++r) {
        int row = bm + wr * 64 + m * 16 + g * 4 + r;
        int col = bn + wc * 64 + n * 16 + l15;
        C[(size_t)row * N + col] = (TC)(acc[m][n][r] * cscale);
      }
}

// ---- DPP rotation reduce across 16-lane rows ----
template <int CTRL>
__device__ inline float dpp_rot(float x) {
  return __builtin_bit_cast(float,
      __builtin_amdgcn_update_dpp(0, __builtin_bit_cast(int, x), CTRL, 0xF, 0xF, true));
}
__device__ inline float red_max16(float x) {
  x = fmaxf(x, dpp_rot<0x121>(x));
  x = fmaxf(x, dpp_rot<0x122>(x));
  x = fmaxf(x, dpp_rot<0x124>(x));
  x = fmaxf(x, dpp_rot<0x128>(x));
  return x;
}
__device__ inline float red_sum16(float x) {
  x += dpp_rot<0x121>(x);
  x += dpp_rot<0x122>(x);
  x += dpp_rot<0x124>(x);
  x += dpp_rot<0x128>(x);
  return x;
}

// ---- Flash attention, causal, online softmax (log2 domain, pre-scaled Q) ----
// QBLK=64, 4 waves (256 thr). Wave w owns q rows qi*64+w*16..+15. 1024 blocks
// (big-first), LDS 49KB -> 3 blocks/CU (12 waves sustained) + 256-block
// backfill queue for dynamic load balance. K double-, V triple-buffered;
// issue-after-barrier 1-ahead; single barrier per KV tile; PV one phase late.
// h = bid&15 => xcd = bid%8 = h%8: each XCD L2 holds only 2 heads' K/V (2MB).
__global__ __launch_bounds__(256) void attn_fwd(const bf16_t* __restrict__ Qp,
                                                const bf16_t* __restrict__ Kp,
                                                const bf16_t* __restrict__ Vt,
                                                bf16_t* __restrict__ Oattn) {
  const int bid = blockIdx.x;
  const int h  = bid & 15;
  const int qi = 63 - (bid >> 4);      // 0..63, big blocks dispatched first
  const int tid = threadIdx.x, lane = tid & 63, w = tid >> 6;
  const int g = lane >> 4, l15 = lane & 15;
  const int qrow = qi * 64 + w * 16;

  __shared__ alignas(16) bf16_t Ks[2][64][64];   // 16 KB, swizzled
  __shared__ alignas(16) bf16_t Vs[3][64][64];   // 24 KB, swizzled
  __shared__ alignas(16) bf16_t Plds[4][16][72]; // 9 KB

  bf16x8 qf[2];
  {
    const bf16_t* qp = &Qp[(size_t)(qrow + l15) * E_DIM + h * 64 + g * 8];
    qf[0] = *(const bf16x8*)qp;
    qf[1] = *(const bf16x8*)(qp + 32);
  }

  // staging: 256 threads x 2 chunks x 16B per K and per V tile (64x64 bf16)
  const int row0 = tid >> 3, c0 = tid & 7;
  const int cgo = (c0 ^ (row0 & 7)) * 8;           // source-side swizzle
  const bf16_t* srcK0 = Kp + (size_t)row0 * E_DIM + h * 64 + cgo;
  const bf16_t* srcK1 = srcK0 + (size_t)32 * E_DIM;       // (row+32)&7 == row&7
  const bf16_t* srcV0 = Vt + (size_t)(h * 64 + row0) * T_DIM + cgo;
  const bf16_t* srcV1 = srcV0 + (size_t)32 * T_DIM;
  bf16_t* KsAll = &Ks[0][0][0];
  bf16_t* VsAll = &Vs[0][0][0];
  const size_t KADV = (size_t)64 * E_DIM;
  const int nt = qi + 1;

  auto issue = [&](int t) {
    bf16_t* kd = KsAll + (t & 1) * 4096;
    bf16_t* vd = VsAll + (t % 3) * 4096;
    gld_lds16(srcK0 + (size_t)t * KADV, kd + tid * 8);
    gld_lds16(srcK1 + (size_t)t * KADV, kd + (256 + tid) * 8);
    gld_lds16(srcV0 + (size_t)t * 64,   vd + tid * 8);
    gld_lds16(srcV1 + (size_t)t * 64,   vd + (256 + tid) * 8);
  };

  f32x4 acc[4] = {};
  float m_r[4], l_p[4];   // l_p: per-lane PARTIAL sum (reduced in epilogue)
#pragma unroll
  for (int r = 0; r < 4; ++r) { m_r[r] = -1e30f; l_p[r] = 0.f; }

  auto pv = [&](int t) {
    const char* Vb = (const char*)(VsAll + (t % 3) * 4096);
    bf16x8 pf0 = *(const bf16x8*)&Plds[w][l15][g * 8];
    bf16x8 pf1 = *(const bf16x8*)&Plds[w][l15][32 + g * 8];
#pragma unroll
    for (int c = 0; c < 4; ++c) {
      const int vr = c * 16 + l15;
      const char* rp = Vb + vr * 128;
      const int sw = (vr & 7) << 4;
      bf16x8 v0 = *(const bf16x8*)(rp + ((g * 16) ^ sw));
      bf16x8 v1 = *(const bf16x8*)(rp + ((64 + g * 16) ^ sw));
      acc[c] = __builtin_amdgcn_mfma_f32_16x16x32_bf16(pf0, v0, acc[c], 0, 0, 0);
      acc[c] = __builtin_amdgcn_mfma_f32_16x16x32_bf16(pf1, v1, acc[c], 0, 0, 0);
    }
  };

  issue(0);

  for (int j = 0; j < nt; ++j) {
    asm volatile("s_waitcnt vmcnt(0)" ::: "memory");
    block_sync();                 // all waves' K_j,V_j resident; phase j-1 done
    if (j + 1 < nt) issue(j + 1); // K_{j+1}->slot (j-1)&1 (reads done), V_{j+1}
                                  // ->slot (j+1)%3 (V_{j-1},V_j untouched)

    __builtin_amdgcn_s_setprio(1);
    if (j > 0) pv(j - 1);         // PV_{j-1}, one phase late

    // QK_j from Ks[j&1]
    const char* Kb = (const char*)(KsAll + (j & 1) * 4096);
    f32x4 s[4] = {};
#pragma unroll
    for (int j16 = 0; j16 < 4; ++j16) {
      const int r0 = j16 * 16 + l15;
      const char* rp = Kb + r0 * 128;
      const int sw = (r0 & 7) << 4;
      bf16x8 k0 = *(const bf16x8*)(rp + ((g * 16) ^ sw));
      bf16x8 k1 = *(const bf16x8*)(rp + ((64 + g * 16) ^ sw));
      s[j16] = __builtin_amdgcn_mfma_f32_16x16x32_bf16(qf[0], k0, s[j16], 0, 0, 0);
      s[j16] = __builtin_amdgcn_mfma_f32_16x16x32_bf16(qf[1], k1, s[j16], 0, 0, 0);
    }
    __builtin_amdgcn_s_setprio(0);

    // causal mask needed only on the diagonal tile (j == nt-1)
    if (j == nt - 1) {
      const int kb = j * 64;
#pragma unroll
      for (int j16 = 0; j16 < 4; ++j16)
#pragma unroll
        for (int r = 0; r < 4; ++r)
          if (kb + j16 * 16 + l15 > qrow + g * 4 + r) s[j16][r] = -1e30f;
    }

    // defer-max: per-lane max is enough to VALIDATE stability; full DPP
    // reduce only in the rescale branch.
    float pmax[4];
#pragma unroll
    for (int r = 0; r < 4; ++r)
      pmax[r] = fmaxf(fmaxf(s[0][r], s[1][r]), fmaxf(s[2][r], s[3][r]));

    int stable = 1;
#pragma unroll
    for (int r = 0; r < 4; ++r) stable &= (pmax[r] <= m_r[r] + 11.0f);
    if (!__all(stable)) {
#pragma unroll
      for (int r = 0; r < 4; ++r) {
        float rm = red_max16(pmax[r]);          // row-uniform
        float mn = fmaxf(m_r[r], rm);
        float sc = fexp2(m_r[r] - mn);
        m_r[r] = mn;
        l_p[r] *= sc;
#pragma unroll
        for (int c = 0; c < 4; ++c) acc[c][r] *= sc;
      }
    }

#pragma unroll
    for (int j16 = 0; j16 < 4; ++j16)
#pragma unroll
      for (int r = 0; r < 4; ++r)
        s[j16][r] = fexp2(s[j16][r] - m_r[r]);

#pragma unroll
    for (int r = 0; r < 4; ++r)
      l_p[r] += s[0][r] + s[1][r] + s[2][r] + s[3][r];   // per-lane partial

    // P -> LDS (bf16) in A-operand layout (per-wave buffer, same-wave use)
#pragma unroll
    for (int j16 = 0; j16 < 4; ++j16)
#pragma unroll
      for (int r = 0; r < 4; ++r)
        Plds[w][g * 4 + r][j16 * 16 + l15] = (bf16_t)s[j16][r];
  }

  // epilogue: PV for the last tile (V_{nt-1} landed at phase nt-1's wait;
  // P written by this wave), then one cross-lane l reduce, then O write.
  pv(nt - 1);

  float l_row[4];
#pragma unroll
  for (int r = 0; r < 4; ++r) l_row[r] = red_sum16(l_p[r]);

#pragma unroll
  for (int c = 0; c < 4; ++c)
#pragma unroll
    for (int r = 0; r < 4; ++r) {
      float o = acc[c][r] / l_row[r];
      Oattn[(size_t)(qrow + g * 4 + r) * E_DIM + h * 64 + c * 16 + l15] = (bf16_t)o;
    }
}

extern "C" void kernel_launch(void* const* d_in, const int* in_sizes, int n_in,
                              void* d_out, int out_size, void* d_ws, size_t ws_size,
                              hipStream_t stream) {
  const float* q  = (const float*)d_in[0];
  const float* k  = (const float*)d_in[1];
  const float* v  = (const float*)d_in[2];
  const float* Wq = (const float*)d_in[3];
  const float* Wk = (const float*)d_in[4];
  const float* Wv = (const float*)d_in[5];
  const float* Wo = (const float*)d_in[6];
  float* out = (float*)d_out;

  const size_t TE = (size_t)T_DIM * E_DIM;   // 4M elems
  const size_t EE = (size_t)E_DIM * E_DIM;   // 1M elems
  dim3 blk(256);

  if (ws_size >= (size_t)56 * 1024 * 1024) {
    bf16_t* qb  = (bf16_t*)d_ws;          // reused as Oa after projections
    bf16_t* kb  = qb + TE;
    bf16_t* vb  = kb + TE;
    bf16_t* Wqb = vb + TE;
    bf16_t* Wkb = Wqb + EE;
    bf16_t* Wvb = Wkb + EE;
    bf16_t* Wob = Wvb + EE;
    bf16_t* Qp  = Wob + EE;
    bf16_t* Kp  = Qp + TE;
    bf16_t* Vt  = Kp + TE;                // [E][T]
    bf16_t* Oa  = qb;                     // alias

    cvt_all<<<2048, blk, 0, stream>>>(q, k, v, Wq, Wk, Wv, Wo,
                                      qb, kb, vb, Wqb, Wkb, Wvb, Wob);
    proj_qkv<<<dim3(768), blk, 0, stream>>>(qb, kb, vb, Wqb, Wkb, Wvb, Qp, Kp, Vt);
    attn_fwd<<<dim3(1024), blk, 0, stream>>>(Qp, Kp, Vt, Oa);
    gemm_fin<<<dim3(8, 64), blk, 0, stream>>>(Oa, Wob, out);
  } else {
    bf16_t* Qp = (bf16_t*)d_ws;
    bf16_t* Kp = Qp + TE;
    bf16_t* Vt = Kp + TE;
    bf16_t* Oa = Vt + TE;
    gemm_bt<float, float, bf16_t><<<dim3(8, 32), blk, 0, stream>>>(q, Wq, Qp, T_DIM, E_DIM, E_DIM, QSCALE_F);
    gemm_bt<float, float, bf16_t><<<dim3(8, 32), blk, 0, stream>>>(k, Wk, Kp, T_DIM, E_DIM, E_DIM, 1.0f);
    gemm_bt<float, float, bf16_t><<<dim3(32, 8), blk, 0, stream>>>(Wv, v, Vt, E_DIM, T_DIM, E_DIM, 1.0f);
    attn_fwd<<<dim3(1024), blk, 0, stream>>>(Qp, Kp, Vt, Oa);
    gemm_bt<bf16_t, float, float><<<dim3(8, 32), blk, 0, stream>>>(Oa, Wo, out, T_DIM, E_DIM, E_DIM, 1.0f);
  }
}

// Round 11
// 140.969 us; speedup vs baseline: 4.1529x; 1.0101x over previous
//
#include <hip/hip_runtime.h>
#include <hip/hip_bf16.h>

// Problem constants (B=1)
#define T_DIM 4096
#define E_DIM 1024
#define H_DIM 16
#define HD_DIM 64
#define LOG2E_F 1.4426950408889634f
#define QSCALE_F (0.125f * LOG2E_F)   // SCALE * log2(e), folded into Qp

typedef __bf16 bf16_t;
typedef __bf16 bf16x8 __attribute__((ext_vector_type(8)));
typedef __bf16 bf16x4 __attribute__((ext_vector_type(4)));
typedef float  f32x4  __attribute__((ext_vector_type(4)));

// ---- helpers ----
__device__ inline void stage8(bf16_t* dst, const float* src) {
  const f32x4* s4 = (const f32x4*)src;
  f32x4 a = s4[0], b = s4[1];
  bf16x8 o;
  o[0] = (bf16_t)a[0]; o[1] = (bf16_t)a[1]; o[2] = (bf16_t)a[2]; o[3] = (bf16_t)a[3];
  o[4] = (bf16_t)b[0]; o[5] = (bf16_t)b[1]; o[6] = (bf16_t)b[2]; o[7] = (bf16_t)b[3];
  *(bf16x8*)dst = o;
}
__device__ inline void stage8(bf16_t* dst, const bf16_t* src) {
  *(bf16x8*)dst = *(const bf16x8*)src;
}

__device__ inline void gld_lds16(const bf16_t* g, bf16_t* l) {
  __builtin_amdgcn_global_load_lds(
      (const __attribute__((address_space(1))) unsigned int*)g,
      (__attribute__((address_space(3))) unsigned int*)l, 16, 0, 0);
}

__device__ inline float fexp2(float x) {  // raw v_exp_f32 (exp2)
  float r;
  asm("v_exp_f32 %0, %1" : "=v"(r) : "v"(x));
  return r;
}

// raw barrier (no implicit vmcnt(0) drain) + compiler memory fence
__device__ inline void block_sync() {
  asm volatile("" ::: "memory");
  __builtin_amdgcn_s_barrier();
  asm volatile("" ::: "memory");
}

// ---- fp32 -> bf16 conversion for all 7 inputs (one launch) ----
__global__ __launch_bounds__(256) void cvt_all(
    const float* __restrict__ q, const float* __restrict__ k, const float* __restrict__ v,
    const float* __restrict__ Wq, const float* __restrict__ Wk,
    const float* __restrict__ Wv, const float* __restrict__ Wo,
    bf16_t* qb, bf16_t* kb, bf16_t* vb,
    bf16_t* Wqb, bf16_t* Wkb, bf16_t* Wvb, bf16_t* Wob) {
  for (int u = blockIdx.x * 256 + threadIdx.x; u < 2097152; u += gridDim.x * 256) {
    const float* s; bf16_t* d; int i;
    if (u < 1572864) {
      int seg = u >> 19, off = u & 524287;
      s = seg == 0 ? q : (seg == 1 ? k : v);
      d = seg == 0 ? qb : (seg == 1 ? kb : vb);
      i = off;
    } else {
      int w = u - 1572864;
      int seg = w >> 17, off = w & 131071;
      s = seg == 0 ? Wq : seg == 1 ? Wk : seg == 2 ? Wv : Wo;
      d = seg == 0 ? Wqb : seg == 1 ? Wkb : seg == 2 ? Wvb : Wob;
      i = off;
    }
    stage8(d + (size_t)i * 8, s + (size_t)i * 8);
  }
}

// ---- bf16 GEMM tile body (m97 structure): C = (A[M][1024] x B[N][1024]^T)*cs
template <int MF, int NF, typename TC>
__device__ __forceinline__ void gemm_body(const bf16_t* __restrict__ A,
                                          const bf16_t* __restrict__ B,
                                          TC* __restrict__ C,
                                          int ldC, int bm, int bn, float cs) {
  constexpr int BM = 32 * MF, BN = 32 * NF;
  __shared__ alignas(16) bf16_t As[BM][64];
  __shared__ alignas(16) bf16_t Bs[BN][64];
  const int tid  = threadIdx.x;
  const int lane = tid & 63, w = tid >> 6;
  const int g = lane >> 4, l15 = lane & 15;
  const int wr = w >> 1, wc = w & 1;

  f32x4 acc[MF][NF] = {};

  for (int kt = 0; kt < 1024; kt += 64) {
    if (kt) __syncthreads();
#pragma unroll
    for (int p = 0; p < MF; ++p) {
      int s = p * 256 + tid;
      int row = s >> 3, c = s & 7;
      int cg = c ^ (row & 7);
      gld_lds16(&A[(size_t)(bm + row) * 1024 + kt + cg * 8], &As[0][0] + s * 8);
    }
#pragma unroll
    for (int p = 0; p < NF; ++p) {
      int s = p * 256 + tid;
      int row = s >> 3, c = s & 7;
      int cg = c ^ (row & 7);
      gld_lds16(&B[(size_t)(bn + row) * 1024 + kt + cg * 8], &Bs[0][0] + s * 8);
    }
    asm volatile("s_waitcnt vmcnt(0)" ::: "memory");
    __syncthreads();

#pragma unroll
    for (int hh = 0; hh < 2; ++hh) {
      bf16x8 af[MF], bfr[NF];
#pragma unroll
      for (int m = 0; m < MF; ++m) {
        int row = wr * (16 * MF) + m * 16 + l15;
        af[m] = *(const bf16x8*)(&As[0][0] + row * 64 + (((hh * 4 + g) ^ (row & 7)) * 8));
      }
#pragma unroll
      for (int n = 0; n < NF; ++n) {
        int row = wc * (16 * NF) + n * 16 + l15;
        bfr[n] = *(const bf16x8*)(&Bs[0][0] + row * 64 + (((hh * 4 + g) ^ (row & 7)) * 8));
      }
#pragma unroll
      for (int m = 0; m < MF; ++m)
#pragma unroll
        for (int n = 0; n < NF; ++n)
          acc[m][n] = __builtin_amdgcn_mfma_f32_16x16x32_bf16(af[m], bfr[n], acc[m][n], 0, 0, 0);
    }
  }

#pragma unroll
  for (int m = 0; m < MF; ++m)
#pragma unroll
    for (int n = 0; n < NF; ++n)
#pragma unroll
      for (int r = 0; r < 4; ++r) {
        int row = bm + wr * (16 * MF) + m * 16 + g * 4 + r;
        int col = bn + wc * (16 * NF) + n * 16 + l15;
        C[(size_t)row * ldC + col] = (TC)(acc[m][n][r] * cs);
      }
}

// ---- fused Q/K/V projections: one launch, 768 blocks (3 blocks/CU) ----
__global__ __launch_bounds__(256) void proj_qkv(
    const bf16_t* __restrict__ qb, const bf16_t* __restrict__ kb,
    const bf16_t* __restrict__ vb,
    const bf16_t* __restrict__ Wqb, const bf16_t* __restrict__ Wkb,
    const bf16_t* __restrict__ Wvb,
    bf16_t* Qp, bf16_t* Kp, bf16_t* Vt) {
  const int bid = blockIdx.x;
  const int which = bid >> 8, t = bid & 255;
  const bf16_t *A, *B; bf16_t* C; int ldC, bm, bn; float cs;
  if (which == 0) {
    A = qb;  B = Wqb; C = Qp; ldC = 1024;
    bm = (t >> 3) * 128; bn = (t & 7) * 128; cs = QSCALE_F;
  } else if (which == 1) {
    A = kb;  B = Wkb; C = Kp; ldC = 1024;
    bm = (t >> 3) * 128; bn = (t & 7) * 128; cs = 1.0f;
  } else {
    A = Wvb; B = vb;  C = Vt; ldC = 4096;
    bm = (t >> 5) * 128; bn = (t & 31) * 128; cs = 1.0f;
  }
  gemm_body<4, 4, bf16_t>(A, B, C, ldC, bm, bn, cs);
}

// ---- final GEMM: out = Oa @ Wo^T, 64x128 tiles (grid 8x64, 2 blocks/CU) ----
__global__ __launch_bounds__(256) void gemm_fin(const bf16_t* __restrict__ A,
                                                const bf16_t* __restrict__ B,
                                                float* __restrict__ C) {
  gemm_body<2, 4, float>(A, B, C, 1024, blockIdx.y * 64, blockIdx.x * 128, 1.0f);
}

// ---- fallback GEMM (fp32 staging, used only if ws too small) ----
template <typename TA, typename TB, typename TC>
__global__ __launch_bounds__(256) void gemm_bt(const TA* __restrict__ A,
                                               const TB* __restrict__ B,
                                               TC* __restrict__ C,
                                               int M, int N, int K, float cscale) {
  __shared__ alignas(16) bf16_t As[128][40];
  __shared__ alignas(16) bf16_t Bs[128][40];
  const int tid  = threadIdx.x;
  const int lane = tid & 63, w = tid >> 6;
  const int g = lane >> 4, l15 = lane & 15;
  const int wr = w >> 1, wc = w & 1;
  const int bm = blockIdx.y * 128, bn = blockIdx.x * 128;

  f32x4 acc[4][4] = {};

  for (int kt = 0; kt < K; kt += 32) {
    __syncthreads();
#pragma unroll
    for (int i = 0; i < 2; ++i) {
      int vv  = tid + i * 256;
      int row = vv >> 2, c8 = (vv & 3) * 8;
      stage8(&As[row][c8], &A[(size_t)(bm + row) * K + kt + c8]);
      stage8(&Bs[row][c8], &B[(size_t)(bn + row) * K + kt + c8]);
    }
    __syncthreads();

    bf16x8 af[4], bfr[4];
#pragma unroll
    for (int m = 0; m < 4; ++m)
      af[m] = *(const bf16x8*)&As[wr * 64 + m * 16 + l15][g * 8];
#pragma unroll
    for (int n = 0; n < 4; ++n)
      bfr[n] = *(const bf16x8*)&Bs[wc * 64 + n * 16 + l15][g * 8];
#pragma unroll
    for (int m = 0; m < 4; ++m)
#pragma unroll
      for (int n = 0; n < 4; ++n)
        acc[m][n] = __builtin_amdgcn_mfma_f32_16x16x32_bf16(af[m], bfr[n], acc[m][n], 0, 0, 0);
  }

#pragma unroll
  for (int m = 0; m < 4; ++m)
#pragma unroll
    for (int n = 0; n < 4; ++n)
#pragma unroll
      for (int r = 0; r < 4; ++r) {
        int row = bm + wr * 64 + m * 16 + g * 4 + r;
        int col = bn + wc * 64 + n * 16 + l15;
        C[(size_t)row * N + col] = (TC)(acc[m][n][r] * cscale);
      }
}

// ---- Flash attention, causal, online softmax (log2 domain, pre-scaled Q) ----
// QBLK=64, 4 waves (256 thr), 1024 blocks big-first; K double-, V triple-
// buffered; single barrier per KV tile; PV one phase late.
// SWAPPED-OPERAND QK^T: s = mfma(K, Q) -> D row = k, col = q. Lane l holds
// q = qrow + l15 and the k-band {16*j16 + 4*g + r}: the full q-row is spread
// across the 4 lanes sharing l15 (g = 0..3). m/l must therefore be reduced
// across that g-quad (__shfl_xor 16, 32) -- per-lane-only m/l was the round
// 9/10 bug (P normalized with 4 different maxes per row).
// P written as 4x ds_write_b64 in [q][k] layout; PV = mfma(V, P) gives O^T.
__global__ __launch_bounds__(256) void attn_fwd(const bf16_t* __restrict__ Qp,
                                                const bf16_t* __restrict__ Kp,
                                                const bf16_t* __restrict__ Vt,
                                                bf16_t* __restrict__ Oattn) {
  const int bid = blockIdx.x;
  const int h  = bid & 15;             // xcd = bid%8 = h%8: 2 heads per XCD L2
  const int qi = 63 - (bid >> 4);      // 0..63, big blocks dispatched first
  const int tid = threadIdx.x, lane = tid & 63, w = tid >> 6;
  const int g = lane >> 4, l15 = lane & 15;
  const int qrow = qi * 64 + w * 16;

  __shared__ alignas(16) bf16_t Ks[2][64][64];   // 16 KB, swizzled
  __shared__ alignas(16) bf16_t Vs[3][64][64];   // 24 KB, swizzled
  __shared__ alignas(16) bf16_t Plds[4][16][72]; // 9 KB, [q][k], 144B stride

  bf16x8 qf[2];
  {
    const bf16_t* qp = &Qp[(size_t)(qrow + l15) * E_DIM + h * 64 + g * 8];
    qf[0] = *(const bf16x8*)qp;
    qf[1] = *(const bf16x8*)(qp + 32);
  }

  // staging: 256 threads x 2 chunks x 16B per K and per V tile (64x64 bf16)
  const int row0 = tid >> 3, c0 = tid & 7;
  const int cgo = (c0 ^ (row0 & 7)) * 8;           // source-side swizzle
  const bf16_t* srcK0 = Kp + (size_t)row0 * E_DIM + h * 64 + cgo;
  const bf16_t* srcK1 = srcK0 + (size_t)32 * E_DIM;       // (row+32)&7 == row&7
  const bf16_t* srcV0 = Vt + (size_t)(h * 64 + row0) * T_DIM + cgo;
  const bf16_t* srcV1 = srcV0 + (size_t)32 * T_DIM;
  bf16_t* KsAll = &Ks[0][0][0];
  bf16_t* VsAll = &Vs[0][0][0];
  const size_t KADV = (size_t)64 * E_DIM;
  const int nt = qi + 1;

  auto issue = [&](int t) {
    bf16_t* kd = KsAll + (t & 1) * 4096;
    bf16_t* vd = VsAll + (t % 3) * 4096;
    gld_lds16(srcK0 + (size_t)t * KADV, kd + tid * 8);
    gld_lds16(srcK1 + (size_t)t * KADV, kd + (256 + tid) * 8);
    gld_lds16(srcV0 + (size_t)t * 64,   vd + tid * 8);
    gld_lds16(srcV1 + (size_t)t * 64,   vd + (256 + tid) * 8);
  };

  f32x4 acc[4] = {};          // acc[c][r]: O^T[d = c*16 + g*4 + r][q = l15]
  float m_s = -1e30f, l_s = 0.f;   // row-uniform across the g-quad

  auto pv = [&](int t) {
    const char* Vb = (const char*)(VsAll + (t % 3) * 4096);
    bf16x8 pf0 = *(const bf16x8*)&Plds[w][l15][g * 8];        // k = g*8..+7
    bf16x8 pf1 = *(const bf16x8*)&Plds[w][l15][32 + g * 8];   // k = 32+g*8..
#pragma unroll
    for (int c = 0; c < 4; ++c) {
      const int vr = c * 16 + l15;
      const char* rp = Vb + vr * 128;
      const int sw = (vr & 7) << 4;
      bf16x8 v0 = *(const bf16x8*)(rp + ((g * 16) ^ sw));
      bf16x8 v1 = *(const bf16x8*)(rp + ((64 + g * 16) ^ sw));
      acc[c] = __builtin_amdgcn_mfma_f32_16x16x32_bf16(v0, pf0, acc[c], 0, 0, 0);
      acc[c] = __builtin_amdgcn_mfma_f32_16x16x32_bf16(v1, pf1, acc[c], 0, 0, 0);
    }
  };

  issue(0);

  for (int j = 0; j < nt; ++j) {
    asm volatile("s_waitcnt vmcnt(0)" ::: "memory");
    block_sync();                 // all waves' K_j,V_j resident; phase j-1 done
    if (j + 1 < nt) issue(j + 1);

    __builtin_amdgcn_s_setprio(1);
    if (j > 0) pv(j - 1);         // PV_{j-1}, one phase late (before rescale!)

    // S^T = K (Q*SCALE*log2e)^T from Ks[j&1]: s[j16][r] is
    // (k = j*64 + 16*j16 + 4*g + r, q = qrow + l15)
    const char* Kb = (const char*)(KsAll + (j & 1) * 4096);
    f32x4 s[4] = {};
#pragma unroll
    for (int j16 = 0; j16 < 4; ++j16) {
      const int r0 = j16 * 16 + l15;
      const char* rp = Kb + r0 * 128;
      const int sw = (r0 & 7) << 4;
      bf16x8 k0 = *(const bf16x8*)(rp + ((g * 16) ^ sw));
      bf16x8 k1 = *(const bf16x8*)(rp + ((64 + g * 16) ^ sw));
      s[j16] = __builtin_amdgcn_mfma_f32_16x16x32_bf16(k0, qf[0], s[j16], 0, 0, 0);
      s[j16] = __builtin_amdgcn_mfma_f32_16x16x32_bf16(k1, qf[1], s[j16], 0, 0, 0);
    }
    __builtin_amdgcn_s_setprio(0);

    // causal mask, diagonal tile only: k > q
    if (j == nt - 1) {
      const int kb = j * 64;
#pragma unroll
      for (int j16 = 0; j16 < 4; ++j16)
#pragma unroll
        for (int r = 0; r < 4; ++r)
          if (kb + j16 * 16 + g * 4 + r > qrow + l15) s[j16][r] = -1e30f;
    }

    // online softmax: per-lane partial max, then reduce across the g-quad
    // (lanes l15 / l15+16 / l15+32 / l15+48 hold the same q-row)
    float pmax = s[0][0];
#pragma unroll
    for (int j16 = 0; j16 < 4; ++j16)
#pragma unroll
      for (int r = 0; r < 4; ++r) pmax = fmaxf(pmax, s[j16][r]);
    pmax = fmaxf(pmax, __shfl_xor(pmax, 16));
    pmax = fmaxf(pmax, __shfl_xor(pmax, 32));   // row-uniform max

    if (!__all(pmax <= m_s + 11.0f)) {
      float mn = fmaxf(m_s, pmax);
      float sc = fexp2(m_s - mn);
      m_s = mn;
      l_s *= sc;
#pragma unroll
      for (int c = 0; c < 4; ++c)
#pragma unroll
        for (int r = 0; r < 4; ++r) acc[c][r] *= sc;
    }

    float ps = 0.f;
#pragma unroll
    for (int j16 = 0; j16 < 4; ++j16)
#pragma unroll
      for (int r = 0; r < 4; ++r) {
        s[j16][r] = fexp2(s[j16][r] - m_s);
        ps += s[j16][r];
      }
    ps += __shfl_xor(ps, 16);
    ps += __shfl_xor(ps, 32);                   // row-uniform partial sum
    l_s += ps;

    // P -> LDS [q][k]: per j16 the 4 r-values are k-consecutive -> b64 write
#pragma unroll
    for (int j16 = 0; j16 < 4; ++j16) {
      bf16x4 pk;
      pk[0] = (bf16_t)s[j16][0]; pk[1] = (bf16_t)s[j16][1];
      pk[2] = (bf16_t)s[j16][2]; pk[3] = (bf16_t)s[j16][3];
      *(bf16x4*)&Plds[w][l15][j16 * 16 + g * 4] = pk;
    }
  }

  // epilogue: PV for the last tile, then O^T write (4 consecutive bf16 per c)
  pv(nt - 1);

  const float inv = 1.0f / l_s;
#pragma unroll
  for (int c = 0; c < 4; ++c) {
    bf16x4 o;
#pragma unroll
    for (int r = 0; r < 4; ++r) o[r] = (bf16_t)(acc[c][r] * inv);
    *(bf16x4*)&Oattn[(size_t)(qrow + l15) * E_DIM + h * 64 + c * 16 + g * 4] = o;
  }
}

extern "C" void kernel_launch(void* const* d_in, const int* in_sizes, int n_in,
                              void* d_out, int out_size, void* d_ws, size_t ws_size,
                              hipStream_t stream) {
  const float* q  = (const float*)d_in[0];
  const float* k  = (const float*)d_in[1];
  const float* v  = (const float*)d_in[2];
  const float* Wq = (const float*)d_in[3];
  const float* Wk = (const float*)d_in[4];
  const float* Wv = (const float*)d_in[5];
  const float* Wo = (const float*)d_in[6];
  float* out = (float*)d_out;

  const size_t TE = (size_t)T_DIM * E_DIM;   // 4M elems
  const size_t EE = (size_t)E_DIM * E_DIM;   // 1M elems
  dim3 blk(256);

  if (ws_size >= (size_t)56 * 1024 * 1024) {
    bf16_t* qb  = (bf16_t*)d_ws;          // reused as Oa after projections
    bf16_t* kb  = qb + TE;
    bf16_t* vb  = kb + TE;
    bf16_t* Wqb = vb + TE;
    bf16_t* Wkb = Wqb + EE;
    bf16_t* Wvb = Wkb + EE;
    bf16_t* Wob = Wvb + EE;
    bf16_t* Qp  = Wob + EE;
    bf16_t* Kp  = Qp + TE;
    bf16_t* Vt  = Kp + TE;                // [E][T]
    bf16_t* Oa  = qb;                     // alias

    cvt_all<<<2048, blk, 0, stream>>>(q, k, v, Wq, Wk, Wv, Wo,
                                      qb, kb, vb, Wqb, Wkb, Wvb, Wob);
    proj_qkv<<<dim3(768), blk, 0, stream>>>(qb, kb, vb, Wqb, Wkb, Wvb, Qp, Kp, Vt);
    attn_fwd<<<dim3(1024), blk, 0, stream>>>(Qp, Kp, Vt, Oa);
    gemm_fin<<<dim3(8, 64), blk, 0, stream>>>(Oa, Wob, out);
  } else {
    bf16_t* Qp = (bf16_t*)d_ws;
    bf16_t* Kp = Qp + TE;
    bf16_t* Vt = Kp + TE;
    bf16_t* Oa = Vt + TE;
    gemm_bt<float, float, bf16_t><<<dim3(8, 32), blk, 0, stream>>>(q, Wq, Qp, T_DIM, E_DIM, E_DIM, QSCALE_F);
    gemm_bt<float, float, bf16_t><<<dim3(8, 32), blk, 0, stream>>>(k, Wk, Kp, T_DIM, E_DIM, E_DIM, 1.0f);
    gemm_bt<float, float, bf16_t><<<dim3(32, 8), blk, 0, stream>>>(Wv, v, Vt, E_DIM, T_DIM, E_DIM, 1.0f);
    attn_fwd<<<dim3(1024), blk, 0, stream>>>(Qp, Kp, Vt, Oa);
    gemm_bt<bf16_t, float, float><<<dim3(8, 32), blk, 0, stream>>>(Oa, Wo, out, T_DIM, E_DIM, E_DIM, 1.0f);
  }
}